// Round 19
// baseline (218.992 us; speedup 1.0000x reference)
//
#include <hip/hip_runtime.h>
#include <hip/hip_bf16.h>

typedef unsigned short u16;
typedef __attribute__((ext_vector_type(4))) float f32x4;
typedef __attribute__((ext_vector_type(8))) short short8;
typedef __attribute__((ext_vector_type(4))) unsigned short ushort4v;

#define LOG2E 1.4426950408889634f

// ---------- helpers ----------
__device__ __forceinline__ u16 f2bfu(float f) {
  unsigned int u = __float_as_uint(f);
  u += 0x7FFFu + ((u >> 16) & 1u);   // RNE
  return (u16)(u >> 16);
}
__device__ __forceinline__ f32x4 mfma16(short8 a, short8 b, f32x4 c) {
  return __builtin_amdgcn_mfma_f32_16x16x32_bf16(a, b, c, 0, 0, 0);
}
__device__ __forceinline__ void gld16(const void* g, void* l) {
  __builtin_amdgcn_global_load_lds(
      (const __attribute__((address_space(1))) void*)g,
      (__attribute__((address_space(3))) void*)l, 16, 0, 0);
}
// DPP row_ror:N within 16-lane rows (VALU-pipe cross-lane; no LDS)
template <int CTRL>
__device__ __forceinline__ float dppf(float x) {
  int xi = __float_as_int(x);
  return __int_as_float(__builtin_amdgcn_update_dpp(xi, xi, CTRL, 0xf, 0xf, false));
}
__device__ __forceinline__ float rsum16(float v) {
  v += dppf<0x121>(v);
  v += dppf<0x122>(v);
  v += dppf<0x124>(v);
  v += dppf<0x128>(v);
  return v;
}

// ---------- fp32 -> bf16 convert, all 7 weights in one launch ----------
__global__ void k_cvt7(const float* __restrict__ s0, const float* __restrict__ s1,
                       const float* __restrict__ s2, const float* __restrict__ s3,
                       const float* __restrict__ s4, const float* __restrict__ s5,
                       const float* __restrict__ s6,
                       u16* __restrict__ d0, u16* __restrict__ d1, u16* __restrict__ d2,
                       u16* __restrict__ d3, u16* __restrict__ d4, u16* __restrict__ d5,
                       u16* __restrict__ d6) {
  const int y = blockIdx.y;
  const float* src; u16* dst; int n4;
  switch (y) {
    case 0: src = s0; dst = d0; n4 = 262144; break;
    case 1: src = s1; dst = d1; n4 = 262144; break;
    case 2: src = s2; dst = d2; n4 = 262144; break;
    case 3: src = s3; dst = d3; n4 = 262144; break;
    case 4: src = s4; dst = d4; n4 = 1048576; break;
    case 5: src = s5; dst = d5; n4 = 1048576; break;
    default: src = s6; dst = d6; n4 = 1048576; break;
  }
  int i = blockIdx.x * blockDim.x + threadIdx.x;
  if (i < n4) {
    float4 v = ((const float4*)src)[i];
    ushort4v o;
    o.x = f2bfu(v.x); o.y = f2bfu(v.y); o.z = f2bfu(v.z); o.w = f2bfu(v.w);
    *(ushort4v*)(dst + (size_t)i * 4) = o;
  }
}

// ---------- fused router + LN1 + residual pre-fill ----------
__global__ void k_router_ln(const float* __restrict__ x, const float* __restrict__ wr,
                            const float* __restrict__ g, const float* __restrict__ bb,
                            float* __restrict__ logits, float* __restrict__ out_lg,
                            float* __restrict__ out_x, u16* __restrict__ xn) {
  int t = blockIdx.x * 4 + (threadIdx.x >> 6);
  int l = threadIdx.x & 63;
  const float* xp = x + (size_t)t * 1024;
  float* op = out_x + (size_t)t * 1024;
  float4 xv[4];
  float s = 0.f, sq = 0.f, lg = 0.f;
#pragma unroll
  for (int p = 0; p < 4; ++p) {
    xv[p] = *(const float4*)(xp + (p * 64 + l) * 4);
    float4 wv = *(const float4*)(wr + (p * 64 + l) * 4);
    lg += xv[p].x * wv.x + xv[p].y * wv.y + xv[p].z * wv.z + xv[p].w * wv.w;
    s += xv[p].x + xv[p].y + xv[p].z + xv[p].w;
    sq += xv[p].x * xv[p].x + xv[p].y * xv[p].y + xv[p].z * xv[p].z + xv[p].w * xv[p].w;
    *(float4*)(op + (p * 64 + l) * 4) = xv[p];
  }
#pragma unroll
  for (int off = 32; off; off >>= 1) {
    lg += __shfl_xor(lg, off);
    s += __shfl_xor(s, off);
    sq += __shfl_xor(sq, off);
  }
  float mu = s * (1.f / 1024.f);
  float var = sq * (1.f / 1024.f) - mu * mu;
  float rs = rsqrtf(var + 1e-6f);
#pragma unroll
  for (int p = 0; p < 4; ++p) {
    float4 gv = *(const float4*)(g + (p * 64 + l) * 4);
    float4 bv = *(const float4*)(bb + (p * 64 + l) * 4);
    ushort4v o;
    o.x = f2bfu((xv[p].x - mu) * rs * gv.x + bv.x);
    o.y = f2bfu((xv[p].y - mu) * rs * gv.y + bv.y);
    o.z = f2bfu((xv[p].z - mu) * rs * gv.z + bv.z);
    o.w = f2bfu((xv[p].w - mu) * rs * gv.w + bv.w);
    *(ushort4v*)(xn + (size_t)t * 1024 + (p * 64 + l) * 4) = o;
  }
  if (l == 0) { logits[t] = lg; out_lg[t] = lg; }
}

// ---------- top-k mask by rank counting (ties: lower index wins) ----------
__global__ void k_mask(const float* __restrict__ logits, float* __restrict__ mask) {
  __shared__ float lg[2048];
  int b = blockIdx.y;
  const float* lp = logits + b * 2048;
  for (int j = threadIdx.x; j < 2048; j += 256) lg[j] = lp[j];
  __syncthreads();
  int t = threadIdx.x >> 2, qtr = threadIdx.x & 3;
  int i = blockIdx.x * 64 + t;
  float my = lg[i];
  int cnt = 0;
  for (int j = qtr * 512; j < qtr * 512 + 512; j += 4) {
    float4 v = *(const float4*)&lg[j];
    cnt += (v.x > my) || (v.x == my && (j + 0) < i);
    cnt += (v.y > my) || (v.y == my && (j + 1) < i);
    cnt += (v.z > my) || (v.z == my && (j + 2) < i);
    cnt += (v.w > my) || (v.w == my && (j + 3) < i);
  }
  cnt += __shfl_xor(cnt, 1);
  cnt += __shfl_xor(cnt, 2);
  if (qtr == 0) mask[b * 2048 + i] = (cnt < 1024) ? 1.0f : 0.0f;
}

// ---------- compact selected-token index (ascending) via prefix scan ----------
__global__ void k_scan(const float* __restrict__ mask, int* __restrict__ idx) {
  __shared__ int wsum[4];
  int b = blockIdx.x;
  const float* mp = mask + b * 2048;
  int t = threadIdx.x, lane = t & 63, wv = t >> 6;
  int sel[8]; int c = 0;
#pragma unroll
  for (int j = 0; j < 8; ++j) { sel[j] = mp[t * 8 + j] > 0.5f; c += sel[j]; }
  int sc = c;
#pragma unroll
  for (int off = 1; off < 64; off <<= 1) {
    int u = __shfl_up(sc, off);
    if (lane >= off) sc += u;
  }
  if (lane == 63) wsum[wv] = sc;
  __syncthreads();
  int woff = 0;
  for (int i = 0; i < wv; ++i) woff += wsum[i];
  int pos = woff + sc - c;   // exclusive prefix
#pragma unroll
  for (int j = 0; j < 8; ++j)
    if (sel[j]) idx[b * 1024 + pos++] = t * 8 + j;
}

// ---------- V transpose: V[b,s,h*64+d] -> VT[bh][d][s] ----------
__global__ void k_vtrans(const u16* __restrict__ V, u16* __restrict__ VT) {
  int bh = blockIdx.y;
  int b = bh >> 4, h = bh & 15;
  int w = threadIdx.x >> 6, l = threadIdx.x & 63;
  int s0 = (blockIdx.x * 4 + w) * 32;
  const u16* vb = V + ((size_t)b * 2048) * 1024 + h * 64 + l;
  u16 vals[32];
#pragma unroll
  for (int j = 0; j < 32; ++j) vals[j] = vb[(size_t)(s0 + j) * 1024];
  u16* ob = VT + ((size_t)bh * 64 + l) * 2048 + s0;
#pragma unroll
  for (int c = 0; c < 4; ++c) {
    short8 o;
#pragma unroll
    for (int j = 0; j < 8; ++j) o[j] = (short)vals[c * 8 + j];
    *(short8*)&ob[c * 8] = o;
  }
}

// ---------- QKV v3: BK=32, 32KB LDS, 3 blocks/CU -> all 640 blocks resident ----------
__global__ __launch_bounds__(256, 3)
void k_qkv2(const u16* __restrict__ A, const int* __restrict__ idx,
            const u16* __restrict__ Wq, const u16* __restrict__ Wk, const u16* __restrict__ Wv,
            u16* __restrict__ Qc, u16* __restrict__ Ko, u16* __restrict__ Vo) {
  __shared__ alignas(16) u16 Al[2][128][32];
  __shared__ alignas(16) u16 Bl[2][128][32];
  const int tid = threadIdx.x, w = tid >> 6, l = tid & 63;
  const int b = blockIdx.x, xcd = b & 7, j = b >> 3;
  const u16* W; u16* Ot; int m0, n0; bool isQ;
  if (j < 16) {
    isQ = true;
    int rowg = (xcd >> 1) * 4 + (j >> 2);
    int col  = (xcd & 1) * 4 + (j & 3);
    m0 = rowg * 128; n0 = col * 128; W = Wq; Ot = Qc;
  } else {
    isQ = false;
    int jj = j - 16;
    int rowg = (xcd >> 1) * 8 + (jj >> 3);
    int colg = (xcd & 1) * 8 + (jj & 7);
    m0 = rowg * 128; n0 = (colg & 7) * 128;
    W = (colg >> 3) ? Wv : Wk; Ot = (colg >> 3) ? Vo : Ko;
  }
  int srow[2];
#pragma unroll
  for (int i = 0; i < 2; ++i) {
    int r = (i * 256 + tid) >> 2;
    int row = m0 + r;
    if (isQ) {
      int b2 = row >> 10;
      srow[i] = b2 * 2048 + idx[b2 * 1024 + (row & 1023)];
    } else srow[i] = row;
  }
  const int wr = (w >> 1) * 64, wc = (w & 1) * 64;
  f32x4 acc[4][4];
#pragma unroll
  for (int mt = 0; mt < 4; ++mt)
#pragma unroll
    for (int nt = 0; nt < 4; ++nt) acc[mt][nt] = (f32x4){0.f, 0.f, 0.f, 0.f};

  auto stage = [&](int bf, int t) {
#pragma unroll
    for (int i = 0; i < 2; ++i) {
      const int c = i * 256 + tid;
      const int r = c >> 2, cc = c & 3;
      gld16(A + (size_t)srow[i] * 1024 + t * 32 + cc * 8, (char*)(&Al[bf][0][0]) + c * 16);
      gld16(W + (size_t)(n0 + r) * 1024 + t * 32 + cc * 8, (char*)(&Bl[bf][0][0]) + c * 16);
    }
  };

  stage(0, 0);
  for (int t = 0; t < 32; ++t) {
    __syncthreads();
    if (t + 1 < 32) stage((t + 1) & 1, t + 1);
    const int bf = t & 1;
    const int ko = (l >> 4) * 8;
    short8 af[4], bv[4];
#pragma unroll
    for (int mt = 0; mt < 4; ++mt) af[mt] = *(const short8*)&Al[bf][wr + mt * 16 + (l & 15)][ko];
#pragma unroll
    for (int nt = 0; nt < 4; ++nt) bv[nt] = *(const short8*)&Bl[bf][wc + nt * 16 + (l & 15)][ko];
#pragma unroll
    for (int mt = 0; mt < 4; ++mt)
#pragma unroll
      for (int nt = 0; nt < 4; ++nt)
        acc[mt][nt] = mfma16(af[mt], bv[nt], acc[mt][nt]);
  }
#pragma unroll
  for (int mt = 0; mt < 4; ++mt)
#pragma unroll
    for (int nt = 0; nt < 4; ++nt) {
      int row = m0 + wr + mt * 16 + ((l >> 4) << 2);
      int colo = n0 + wc + nt * 16 + (l & 15);
#pragma unroll
      for (int r = 0; r < 4; ++r)
        Ot[(size_t)(row + r) * 1024 + colo] = f2bfu(acc[mt][nt][r]);
    }
}

// ---------- split-K projection v2: 512 threads, 8 waves x 64x32 sub-tiles ----------
// 16 waves/CU at 2 blocks/CU; acc[4][2]=32 VGPR/wave; 64KB LDS; grid 512 exact.
__global__ __launch_bounds__(512, 2)
void k_projsk(const u16* __restrict__ A, const u16* __restrict__ W,
              float* __restrict__ P0, float* __restrict__ P1,
              float* __restrict__ P2, float* __restrict__ P3,
              int K, int slice) {
  __shared__ alignas(16) u16 Al[2][128][64];
  __shared__ alignas(16) u16 Bl[2][128][64];
  const int tid = threadIdx.x, w = tid >> 6, l = tid & 63;
  const int b = blockIdx.x, xcd = b & 7, k = b >> 3;
  const int pair = xcd * 8 + (k >> 3);
  const int rowg = pair >> 2, z = pair & 3, col = k & 7;
  const int n0 = col * 128, m0 = rowg * 128, k0 = z * slice;
  float* P = z == 0 ? P0 : (z == 1 ? P1 : (z == 2 ? P2 : P3));
  const int wr = (w >> 2) * 64, wc = (w & 3) * 32;   // 2x4 grid of 64x32 sub-tiles
  f32x4 acc[4][2];
#pragma unroll
  for (int mt = 0; mt < 4; ++mt)
#pragma unroll
    for (int nt = 0; nt < 2; ++nt) acc[mt][nt] = (f32x4){0.f, 0.f, 0.f, 0.f};
  const int nsteps = slice >> 6;

  // stage: tile = 128x64 u16 = 1024 chunks of 16B; 512 threads -> 2 chunks each
  auto stage = [&](int bf, int t) {
#pragma unroll
    for (int i = 0; i < 2; ++i) {
      const int c = i * 512 + tid;
      const int row = c >> 3, cc = c & 7;
      gld16(A + (size_t)(m0 + row) * K + k0 + t * 64 + cc * 8, (char*)(&Al[bf][0][0]) + c * 16);
      gld16(W + (size_t)(n0 + row) * K + k0 + t * 64 + cc * 8, (char*)(&Bl[bf][0][0]) + c * 16);
    }
  };

  stage(0, 0);
  for (int t = 0; t < nsteps; ++t) {
    __syncthreads();
    if (t + 1 < nsteps) stage((t + 1) & 1, t + 1);
    const int bf = t & 1;
#pragma unroll
    for (int kk = 0; kk < 2; ++kk) {
      const int ko = kk * 32 + (l >> 4) * 8;
      short8 af[4], bv[2];
#pragma unroll
      for (int mt = 0; mt < 4; ++mt) af[mt] = *(const short8*)&Al[bf][wr + mt * 16 + (l & 15)][ko];
#pragma unroll
      for (int nt = 0; nt < 2; ++nt) bv[nt] = *(const short8*)&Bl[bf][wc + nt * 16 + (l & 15)][ko];
#pragma unroll
      for (int mt = 0; mt < 4; ++mt)
#pragma unroll
        for (int nt = 0; nt < 2; ++nt)
          acc[mt][nt] = mfma16(af[mt], bv[nt], acc[mt][nt]);
    }
  }
#pragma unroll
  for (int mt = 0; mt < 4; ++mt)
#pragma unroll
    for (int nt = 0; nt < 2; ++nt) {
      int row = m0 + wr + mt * 16 + ((l >> 4) << 2);
      int colo = n0 + wc + nt * 16 + (l & 15);
#pragma unroll
      for (int r = 0; r < 4; ++r)
        P[(size_t)(row + r) * 1024 + colo] = acc[mt][nt][r];
    }
}

// ---------- combine Z=4 partials + residual, scatter (down-proj final) ----------
__global__ void k_combine(const float* __restrict__ P0, const float* __restrict__ P1,
                          const float* __restrict__ P2, const float* __restrict__ P3,
                          const int* __restrict__ idx, const float* __restrict__ resid,
                          float* __restrict__ out) {
  int slot = blockIdx.x * 2 + (threadIdx.x >> 7);
  int c0 = (threadIdx.x & 127) * 8;
  int b = slot >> 10;
  int orig = idx[b * 1024 + (slot & 1023)];
  size_t po = (size_t)slot * 1024 + c0;
  size_t go = ((size_t)(b * 2048 + orig)) * 1024 + c0;
#pragma unroll
  for (int h = 0; h < 2; ++h) {
    float4 a = *(const float4*)(P0 + po + h * 4);
    float4 bb = *(const float4*)(P1 + po + h * 4);
    float4 c = *(const float4*)(P2 + po + h * 4);
    float4 d = *(const float4*)(P3 + po + h * 4);
    float4 rr = *(const float4*)(resid + go + h * 4);
    float4 o;
    o.x = rr.x + a.x + bb.x + c.x + d.x;
    o.y = rr.y + a.y + bb.y + c.y + d.y;
    o.z = rr.z + a.z + bb.z + c.z + d.z;
    o.w = rr.w + a.w + bb.w + c.w + d.w;
    *(float4*)(out + go + h * 4) = o;
  }
}

// ---------- fused combine(o-proj) + LN2: out_x = x + sum(P); xn2 = LN(out_x) compact ----------
__global__ void k_combine_ln(const float* __restrict__ P0, const float* __restrict__ P1,
                             const float* __restrict__ P2, const float* __restrict__ P3,
                             const int* __restrict__ idx, const float* __restrict__ resid,
                             const float* __restrict__ g, const float* __restrict__ bb,
                             float* __restrict__ out, u16* __restrict__ xn2) {
  __shared__ float red[2][2][2];
  int sh = threadIdx.x >> 7;
  int slot = blockIdx.x * 2 + sh;
  int tl = threadIdx.x & 127;
  int c0 = tl * 8;
  int b = slot >> 10;
  int orig = idx[b * 1024 + (slot & 1023)];
  size_t po = (size_t)slot * 1024 + c0;
  size_t go = ((size_t)(b * 2048 + orig)) * 1024 + c0;
  float v[8];
  float s = 0.f, sq = 0.f;
#pragma unroll
  for (int h = 0; h < 2; ++h) {
    float4 a = *(const float4*)(P0 + po + h * 4);
    float4 b4 = *(const float4*)(P1 + po + h * 4);
    float4 c = *(const float4*)(P2 + po + h * 4);
    float4 d = *(const float4*)(P3 + po + h * 4);
    float4 rr = *(const float4*)(resid + go + h * 4);
    float4 o;
    o.x = rr.x + a.x + b4.x + c.x + d.x;
    o.y = rr.y + a.y + b4.y + c.y + d.y;
    o.z = rr.z + a.z + b4.z + c.z + d.z;
    o.w = rr.w + a.w + b4.w + c.w + d.w;
    *(float4*)(out + go + h * 4) = o;
    v[h * 4 + 0] = o.x; v[h * 4 + 1] = o.y; v[h * 4 + 2] = o.z; v[h * 4 + 3] = o.w;
    s += o.x + o.y + o.z + o.w;
    sq += o.x * o.x + o.y * o.y + o.z * o.z + o.w * o.w;
  }
#pragma unroll
  for (int off = 32; off; off >>= 1) { s += __shfl_xor(s, off); sq += __shfl_xor(sq, off); }
  if ((tl & 63) == 0) { red[sh][tl >> 6][0] = s; red[sh][tl >> 6][1] = sq; }
  __syncthreads();
  float ts = red[sh][0][0] + red[sh][1][0];
  float tsq = red[sh][0][1] + red[sh][1][1];
  float mu = ts * (1.f / 1024.f);
  float var = tsq * (1.f / 1024.f) - mu * mu;
  float rs = rsqrtf(var + 1e-6f);
#pragma unroll
  for (int h = 0; h < 2; ++h) {
    float4 gv = *(const float4*)(g + c0 + h * 4);
    float4 bv = *(const float4*)(bb + c0 + h * 4);
    ushort4v o;
    o.x = f2bfu((v[h * 4 + 0] - mu) * rs * gv.x + bv.x);
    o.y = f2bfu((v[h * 4 + 1] - mu) * rs * gv.y + bv.y);
    o.z = f2bfu((v[h * 4 + 2] - mu) * rs * gv.z + bv.z);
    o.w = f2bfu((v[h * 4 + 3] - mu) * rs * gv.w + bv.w);
    *(ushort4v*)(xn2 + (size_t)slot * 1024 + c0 + h * 4) = o;
  }
}

// ---------- ffn_dual v2: 512 threads, gate/up wave-split, 16 waves/CU ----------
__global__ __launch_bounds__(512, 2)
void k_ffn_dual(const u16* __restrict__ A, const u16* __restrict__ Wg, const u16* __restrict__ Wu,
                u16* __restrict__ H, int N, int K) {
  __shared__ alignas(16) char lds[65536];
  u16 (*Al)[128][32]  = (u16(*)[128][32])(lds);            // 16 KB
  u16 (*Bgl)[128][32] = (u16(*)[128][32])(lds + 16384);    // 16 KB
  u16 (*Bul)[128][32] = (u16(*)[128][32])(lds + 32768);    // 16 KB
  float (*ex)[64]     = (float(*)[64])(lds);               // [256][64] f32 = 64 KB (post-loop)
  const int tid = threadIdx.x, w = tid >> 6, l = tid & 63;
  const int b = blockIdx.x, xcd = b & 7, k = b >> 3;
  const int rowg = (xcd >> 2) * 8 + (k >> 3);   // 0..15
  const int col  = (xcd & 3) * 8 + (k & 7);     // 0..31
  const int n0 = col * 128, m0 = rowg * 128;
  const int q = w & 3;                          // quadrant within 128x128
  const int wr = (q >> 1) * 64, wc = (q & 1) * 64;
  const bool isGate = w < 4;
  f32x4 acc[4][4];
#pragma unroll
  for (int mt = 0; mt < 4; ++mt)
#pragma unroll
    for (int nt = 0; nt < 4; ++nt) acc[mt][nt] = (f32x4){0.f, 0.f, 0.f, 0.f};
  const int nsteps = K >> 5;

  const int srow = tid >> 2, scc = tid & 3;
  auto stage = [&](int bf, int t) {
    gld16(A  + (size_t)(m0 + srow) * K + t * 32 + scc * 8, (char*)(&Al[bf][0][0])  + tid * 16);
    gld16(Wg + (size_t)(n0 + srow) * K + t * 32 + scc * 8, (char*)(&Bgl[bf][0][0]) + tid * 16);
    gld16(Wu + (size_t)(n0 + srow) * K + t * 32 + scc * 8, (char*)(&Bul[bf][0][0]) + tid * 16);
  };

  stage(0, 0);
  for (int t = 0; t < nsteps; ++t) {
    __syncthreads();
    if (t + 1 < nsteps) stage((t + 1) & 1, t + 1);
    const int bf = t & 1;
    const int ko = (l >> 4) * 8;
    short8 af[4], bv[4];
#pragma unroll
    for (int mt = 0; mt < 4; ++mt) af[mt] = *(const short8*)&Al[bf][wr + mt * 16 + (l & 15)][ko];
    if (isGate) {
#pragma unroll
      for (int nt = 0; nt < 4; ++nt) bv[nt] = *(const short8*)&Bgl[bf][wc + nt * 16 + (l & 15)][ko];
    } else {
#pragma unroll
      for (int nt = 0; nt < 4; ++nt) bv[nt] = *(const short8*)&Bul[bf][wc + nt * 16 + (l & 15)][ko];
    }
#pragma unroll
    for (int mt = 0; mt < 4; ++mt)
#pragma unroll
      for (int nt = 0; nt < 4; ++nt)
        acc[mt][nt] = mfma16(af[mt], bv[nt], acc[mt][nt]);
  }

  __syncthreads();
  if (!isGate) {
#pragma unroll
    for (int mt = 0; mt < 4; ++mt)
#pragma unroll
      for (int nt = 0; nt < 4; ++nt)
#pragma unroll
        for (int r = 0; r < 4; ++r)
          ex[((q * 4 + mt) * 4 + nt) * 4 + r][l] = acc[mt][nt][r];
  }
  __syncthreads();
  if (isGate) {
#pragma unroll
    for (int mt = 0; mt < 4; ++mt)
#pragma unroll
      for (int nt = 0; nt < 4; ++nt) {
        int row = m0 + wr + mt * 16 + ((l >> 4) << 2);
        int col2 = n0 + wc + nt * 16 + (l & 15);
#pragma unroll
        for (int r = 0; r < 4; ++r) {
          float gv = acc[mt][nt][r];
          float uu = ex[((q * 4 + mt) * 4 + nt) * 4 + r][l];
          float sg = gv / (1.f + __expf(-gv));
          H[(size_t)(row + r) * N + col2] = f2bfu(sg * uu);
        }
      }
  }
}

// ---------- flash attention v9: fixed-shift softmax (no online max) ----------
__global__ __launch_bounds__(512, 2)
void k_attn(const u16* __restrict__ Q, const u16* __restrict__ K,
            const u16* __restrict__ VT, const int* __restrict__ idx,
            u16* __restrict__ O) {
  const int S = 2048, HH = 1024;
  const int px = blockIdx.x, bh = blockIdx.y;
  const int qt = (bh < 16) ? (15 - px) : px;   // complementary across grid halves
  const int b = bh >> 4, h = bh & 15;
  const int tid = threadIdx.x;
  const int g = tid >> 8;
  const int tg = tid & 255;
  const int w = tg >> 6;
  const int l = tid & 63;
  __shared__ alignas(16) u16 Kl[2][64][72];
  __shared__ alignas(16) u16 Vtl[2][64][72];
  __shared__ alignas(16) char un[20480];           // union: Pl [8][16][72] u16 | cm [4][64][20] f32
  u16 (*Pl)[16][72] = (u16(*)[16][72])un;
  float (*cm)[64][20] = (float(*)[64][20])un;
  const size_t base = ((size_t)b * S) * HH + h * 64;
  const size_t qbase = ((size_t)b * 1024) * HH + h * 64;
  const u16* vtb = VT + ((size_t)bh * 64) * S;
  const int* ib = idx + b * 1024;

  const int r0 = tg >> 3,          cc0 = (tg & 7) * 8;
  const int r1 = (256 + tg) >> 3,  cc1 = (tg & 7) * 8;

  const int slot0 = qt * 64 + w * 16 + ((l >> 4) << 2);
  const int slotA = qt * 64 + w * 16 + (l & 15);
  int qp[4];
#pragma unroll
  for (int r = 0; r < 4; ++r) qp[r] = ib[slot0 + r];
  const int nkt = (ib[qt * 64 + 63] >> 6) + 1;
  const int hh = (nkt + 1) >> 1;
  const int kt_base = g ? hh : 0;
  const int kt_end  = g ? nkt : hh;

  short8 qf[2];
#pragma unroll
  for (int kk = 0; kk < 2; ++kk)
    qf[kk] = *(const short8*)&Q[qbase + (size_t)slotA * HH + kk * 32 + (l >> 4) * 8];

  f32x4 accO[4];
  float ls[4];
#pragma unroll
  for (int dt = 0; dt < 4; ++dt) accO[dt] = (f32x4){0.f, 0.f, 0.f, 0.f};
#pragma unroll
  for (int r = 0; r < 4; ++r) ls[r] = 0.f;

  short8 kreg0, kreg1, vreg0, vreg1;
  auto loadregs = [&](int kt) {
    kreg0 = *(const short8*)&K[base + (size_t)(kt * 64 + r0) * HH + cc0];
    kreg1 = *(const short8*)&K[base + (size_t)(kt * 64 + r1) * HH + cc1];
    vreg0 = *(const short8*)&vtb[(size_t)r0 * S + kt * 64 + cc0];
    vreg1 = *(const short8*)&vtb[(size_t)r1 * S + kt * 64 + cc1];
  };
  if (kt_base < kt_end) loadregs(kt_base);

  for (int i = 0; i < hh; ++i) {
    const int kt = kt_base + i;
    const bool valid = kt < kt_end;
    __syncthreads();
    if (valid) {
      *(short8*)&Kl[g][r0][cc0]  = kreg0;
      *(short8*)&Kl[g][r1][cc1]  = kreg1;
      *(short8*)&Vtl[g][r0][cc0] = vreg0;
      *(short8*)&Vtl[g][r1][cc1] = vreg1;
      if (kt + 1 < kt_end) loadregs(kt + 1);
    }
    __syncthreads();
    if (!valid) continue;

    float p[4][4];
    const int kcb = kt * 64 + (l & 15);
#pragma unroll
    for (int ct = 0; ct < 4; ++ct) {
      f32x4 a = (f32x4){0.f, 0.f, 0.f, 0.f};
#pragma unroll
      for (int kk = 0; kk < 2; ++kk) {
        short8 kf = *(const short8*)&Kl[g][ct * 16 + (l & 15)][kk * 32 + (l >> 4) * 8];
        a = mfma16(qf[kk], kf, a);
      }
#pragma unroll
      for (int r = 0; r < 4; ++r) {
        float v = a[r] * (0.125f * LOG2E) - 16.0f;   // fixed shift C=16
        if ((kcb + ct * 16) > qp[r]) v = -1e30f;      // exp2 -> exactly 0
        p[ct][r] = v;
      }
    }
#pragma unroll
    for (int r = 0; r < 4; ++r) {
      float ps = 0.f;
#pragma unroll
      for (int ct = 0; ct < 4; ++ct) { float e = exp2f(p[ct][r]); p[ct][r] = e; ps += e; }
      ps = rsum16(ps);                        // DPP row-reduce
      ls[r] += ps;
    }
#pragma unroll
    for (int ct = 0; ct < 4; ++ct)
#pragma unroll
      for (int r = 0; r < 4; ++r)
        Pl[g * 4 + w][((l >> 4) << 2) + r][ct * 16 + (l & 15)] = f2bfu(p[ct][r]);
    short8 pa[2];
#pragma unroll
    for (int kk = 0; kk < 2; ++kk)
      pa[kk] = *(const short8*)&Pl[g * 4 + w][l & 15][kk * 32 + (l >> 4) * 8];
#pragma unroll
    for (int dt = 0; dt < 4; ++dt)
#pragma unroll
      for (int kk = 0; kk < 2; ++kk) {
        short8 vf = *(const short8*)&Vtl[g][dt * 16 + (l & 15)][kk * 32 + (l >> 4) * 8];
        accO[dt] = mfma16(pa[kk], vf, accO[dt]);
      }
  }

  // combine group partials: same fixed shift on both sides -> plain sums.
  __syncthreads();
  if (g == 1) {
    float* dst = &cm[w][l][0];
#pragma unroll
    for (int r = 0; r < 4; ++r) dst[r] = ls[r];
#pragma unroll
    for (int dt = 0; dt < 4; ++dt)
#pragma unroll
      for (int r = 0; r < 4; ++r) dst[4 + dt * 4 + r] = accO[dt][r];
  }
  __syncthreads();
  if (g == 0) {
    const float* src = &cm[w][l][0];
#pragma unroll
    for (int r = 0; r < 4; ++r) {
      float lsf = ls[r] + src[r];
      float inv = 1.f / lsf;
#pragma unroll
      for (int dt = 0; dt < 4; ++dt) {
        float v = (accO[dt][r] + src[4 + dt * 4 + r]) * inv;
        O[((size_t)(b * 1024 + slot0 + r)) * HH + h * 64 + dt * 16 + (l & 15)] = f2bfu(v);
      }
    }
  }
}

extern "C" void kernel_launch(void* const* d_in, const int* in_sizes, int n_in,
                              void* d_out, int out_size, void* d_ws, size_t ws_size,
                              hipStream_t stream) {
  const float* x  = (const float*)d_in[0];
  const float* wr = (const float*)d_in[1];
  const float* g1 = (const float*)d_in[2];
  const float* b1 = (const float*)d_in[3];
  const float* wq = (const float*)d_in[4];
  const float* wk = (const float*)d_in[5];
  const float* wv = (const float*)d_in[6];
  const float* wo = (const float*)d_in[7];
  const float* g2 = (const float*)d_in[8];
  const float* b2 = (const float*)d_in[9];
  const float* wg = (const float*)d_in[10];
  const float* wu = (const float*)d_in[11];
  const float* wd = (const float*)d_in[12];

  float* out_x  = (float*)d_out;
  float* out_lg = out_x + (size_t)4096 * 1024;

  char* p = (char*)d_ws;
  float* mask   = (float*)p;             p += 16384;
  float* logits = (float*)p;             p += 16384;
  int*   idx    = (int*)p;               p += 16384;   // [2][1024]
  u16* wq_b = (u16*)p;                   p += (size_t)1048576 * 2;
  u16* wk_b = (u16*)p;                   p += (size_t)1048576 * 2;
  u16* wv_b = (u16*)p;                   p += (size_t)1048576 * 2;
  u16* wo_b = (u16*)p;                   p += (size_t)1048576 * 2;
  u16* wg_b = (u16*)p;                   p += (size_t)4194304 * 2;
  u16* wu_b = (u16*)p;                   p += (size_t)4194304 * 2;
  u16* wd_b = (u16*)p;                   p += (size_t)4194304 * 2;
  u16* xn   = (u16*)p;                   p += (size_t)4194304 * 2;  // 8 MB
  u16* q_b  = (u16*)p;                   p += (size_t)4194304 * 2;  // 8 MB
  u16* k_b  = (u16*)p;                   p += (size_t)4194304 * 2;  // 8 MB
  u16* v_b  = (u16*)p;                   p += (size_t)4194304 * 2;  // 8 MB
  u16* ao_b = (u16*)p;                   p += (size_t)2097152 * 2;  // compact [2048][1024]
  u16* vt_b = (u16*)p;                   p += (size_t)4194304 * 2;  // VT, 8 MB
  float* pextra = (float*)p;             p += (size_t)2097152 * 4;  // 8 MB partial
  u16* h_b  = q_b;  // compact h [2048][4096] bf16 spans q_b+k_b (16 MB)

  // o-proj partials (dead after attn): v_b, k_b, vt_b, pextra
  float* oP0 = (float*)v_b;  float* oP1 = (float*)k_b;
  float* oP2 = (float*)vt_b; float* oP3 = pextra;
  u16* xn2 = xn;             // compact [2048][1024] bf16 in xn region front 4 MB
  // down-proj partials (dead after ffn_dual): v_b, vt_b, pextra, xn
  float* dP0 = (float*)v_b;  float* dP1 = (float*)vt_b;
  float* dP2 = pextra;       float* dP3 = (float*)xn;

  // weight conversions (single launch)
  k_cvt7<<<dim3(4096, 7), 256, 0, stream>>>(wq, wk, wv, wo, wg, wu, wd,
                                            wq_b, wk_b, wv_b, wo_b, wg_b, wu_b, wd_b);

  // fused router + LN1 (+ out_x = x pre-fill), then mask + compact index
  k_router_ln<<<1024, 256, 0, stream>>>(x, wr, g1, b1, logits, out_lg, out_x, xn);
  k_mask<<<dim3(32, 2), 256, 0, stream>>>(logits, mask);
  k_scan<<<2, 256, 0, stream>>>(mask, idx);

  // attention sub-block (Q compact, K/V full)
  k_qkv2<<<640, 256, 0, stream>>>(xn, idx, wq_b, wk_b, wv_b, q_b, k_b, v_b);
  k_vtrans<<<dim3(16, 32), 256, 0, stream>>>(v_b, vt_b);
  k_attn<<<dim3(16, 32), 512, 0, stream>>>(q_b, k_b, vt_b, idx, ao_b);
  // o-proj: split-K=4 partials (slice 256), then fused combine + LN2 -> out_x, xn2
  k_projsk<<<512, 512, 0, stream>>>(ao_b, wo_b, oP0, oP1, oP2, oP3, 1024, 256);
  k_combine_ln<<<1024, 256, 0, stream>>>(oP0, oP1, oP2, oP3, idx, x, g2, b2, out_x, xn2);

  // FFN sub-block (compact M=2048, gate/up wave-split)
  k_ffn_dual<<<512, 512, 0, stream>>>(xn2, wg_b, wu_b, h_b, 4096, 1024);
  // down-proj: split-K=4 partials (slice 1024) + combine with resid = out_x (in place)
  k_projsk<<<512, 512, 0, stream>>>(h_b, wd_b, dP0, dP1, dP2, dP3, 4096, 1024);
  k_combine<<<1024, 256, 0, stream>>>(dP0, dP1, dP2, dP3, idx, out_x, out_x);
}

// Round 20
// 216.541 us; speedup vs baseline: 1.0113x; 1.0113x over previous
//
#include <hip/hip_runtime.h>
#include <hip/hip_bf16.h>

typedef unsigned short u16;
typedef __attribute__((ext_vector_type(4))) float f32x4;
typedef __attribute__((ext_vector_type(8))) short short8;
typedef __attribute__((ext_vector_type(4))) unsigned short ushort4v;

#define LOG2E 1.4426950408889634f

// ---------- helpers ----------
__device__ __forceinline__ u16 f2bfu(float f) {
  unsigned int u = __float_as_uint(f);
  u += 0x7FFFu + ((u >> 16) & 1u);   // RNE
  return (u16)(u >> 16);
}
__device__ __forceinline__ f32x4 mfma16(short8 a, short8 b, f32x4 c) {
  return __builtin_amdgcn_mfma_f32_16x16x32_bf16(a, b, c, 0, 0, 0);
}
__device__ __forceinline__ void gld16(const void* g, void* l) {
  __builtin_amdgcn_global_load_lds(
      (const __attribute__((address_space(1))) void*)g,
      (__attribute__((address_space(3))) void*)l, 16, 0, 0);
}
// DPP row_ror:N within 16-lane rows (VALU-pipe cross-lane; no LDS)
template <int CTRL>
__device__ __forceinline__ float dppf(float x) {
  int xi = __float_as_int(x);
  return __int_as_float(__builtin_amdgcn_update_dpp(xi, xi, CTRL, 0xf, 0xf, false));
}
__device__ __forceinline__ float rsum16(float v) {
  v += dppf<0x121>(v);
  v += dppf<0x122>(v);
  v += dppf<0x124>(v);
  v += dppf<0x128>(v);
  return v;
}

// ---------- fp32 -> bf16 convert, all 7 weights in one launch ----------
__global__ void k_cvt7(const float* __restrict__ s0, const float* __restrict__ s1,
                       const float* __restrict__ s2, const float* __restrict__ s3,
                       const float* __restrict__ s4, const float* __restrict__ s5,
                       const float* __restrict__ s6,
                       u16* __restrict__ d0, u16* __restrict__ d1, u16* __restrict__ d2,
                       u16* __restrict__ d3, u16* __restrict__ d4, u16* __restrict__ d5,
                       u16* __restrict__ d6) {
  const int y = blockIdx.y;
  const float* src; u16* dst; int n4;
  switch (y) {
    case 0: src = s0; dst = d0; n4 = 262144; break;
    case 1: src = s1; dst = d1; n4 = 262144; break;
    case 2: src = s2; dst = d2; n4 = 262144; break;
    case 3: src = s3; dst = d3; n4 = 262144; break;
    case 4: src = s4; dst = d4; n4 = 1048576; break;
    case 5: src = s5; dst = d5; n4 = 1048576; break;
    default: src = s6; dst = d6; n4 = 1048576; break;
  }
  int i = blockIdx.x * blockDim.x + threadIdx.x;
  if (i < n4) {
    float4 v = ((const float4*)src)[i];
    ushort4v o;
    o.x = f2bfu(v.x); o.y = f2bfu(v.y); o.z = f2bfu(v.z); o.w = f2bfu(v.w);
    *(ushort4v*)(dst + (size_t)i * 4) = o;
  }
}

// ---------- fused router + LN1 + residual pre-fill ----------
__global__ void k_router_ln(const float* __restrict__ x, const float* __restrict__ wr,
                            const float* __restrict__ g, const float* __restrict__ bb,
                            float* __restrict__ logits, float* __restrict__ out_lg,
                            float* __restrict__ out_x, u16* __restrict__ xn) {
  int t = blockIdx.x * 4 + (threadIdx.x >> 6);
  int l = threadIdx.x & 63;
  const float* xp = x + (size_t)t * 1024;
  float* op = out_x + (size_t)t * 1024;
  float4 xv[4];
  float s = 0.f, sq = 0.f, lg = 0.f;
#pragma unroll
  for (int p = 0; p < 4; ++p) {
    xv[p] = *(const float4*)(xp + (p * 64 + l) * 4);
    float4 wv = *(const float4*)(wr + (p * 64 + l) * 4);
    lg += xv[p].x * wv.x + xv[p].y * wv.y + xv[p].z * wv.z + xv[p].w * wv.w;
    s += xv[p].x + xv[p].y + xv[p].z + xv[p].w;
    sq += xv[p].x * xv[p].x + xv[p].y * xv[p].y + xv[p].z * xv[p].z + xv[p].w * xv[p].w;
    *(float4*)(op + (p * 64 + l) * 4) = xv[p];
  }
#pragma unroll
  for (int off = 32; off; off >>= 1) {
    lg += __shfl_xor(lg, off);
    s += __shfl_xor(s, off);
    sq += __shfl_xor(sq, off);
  }
  float mu = s * (1.f / 1024.f);
  float var = sq * (1.f / 1024.f) - mu * mu;
  float rs = rsqrtf(var + 1e-6f);
#pragma unroll
  for (int p = 0; p < 4; ++p) {
    float4 gv = *(const float4*)(g + (p * 64 + l) * 4);
    float4 bv = *(const float4*)(bb + (p * 64 + l) * 4);
    ushort4v o;
    o.x = f2bfu((xv[p].x - mu) * rs * gv.x + bv.x);
    o.y = f2bfu((xv[p].y - mu) * rs * gv.y + bv.y);
    o.z = f2bfu((xv[p].z - mu) * rs * gv.z + bv.z);
    o.w = f2bfu((xv[p].w - mu) * rs * gv.w + bv.w);
    *(ushort4v*)(xn + (size_t)t * 1024 + (p * 64 + l) * 4) = o;
  }
  if (l == 0) { logits[t] = lg; out_lg[t] = lg; }
}

// ---------- top-k mask by rank counting (ties: lower index wins) ----------
__global__ void k_mask(const float* __restrict__ logits, float* __restrict__ mask) {
  __shared__ float lg[2048];
  int b = blockIdx.y;
  const float* lp = logits + b * 2048;
  for (int j = threadIdx.x; j < 2048; j += 256) lg[j] = lp[j];
  __syncthreads();
  int t = threadIdx.x >> 2, qtr = threadIdx.x & 3;
  int i = blockIdx.x * 64 + t;
  float my = lg[i];
  int cnt = 0;
  for (int j = qtr * 512; j < qtr * 512 + 512; j += 4) {
    float4 v = *(const float4*)&lg[j];
    cnt += (v.x > my) || (v.x == my && (j + 0) < i);
    cnt += (v.y > my) || (v.y == my && (j + 1) < i);
    cnt += (v.z > my) || (v.z == my && (j + 2) < i);
    cnt += (v.w > my) || (v.w == my && (j + 3) < i);
  }
  cnt += __shfl_xor(cnt, 1);
  cnt += __shfl_xor(cnt, 2);
  if (qtr == 0) mask[b * 2048 + i] = (cnt < 1024) ? 1.0f : 0.0f;
}

// ---------- compact selected-token index (ascending) via prefix scan ----------
__global__ void k_scan(const float* __restrict__ mask, int* __restrict__ idx) {
  __shared__ int wsum[4];
  int b = blockIdx.x;
  const float* mp = mask + b * 2048;
  int t = threadIdx.x, lane = t & 63, wv = t >> 6;
  int sel[8]; int c = 0;
#pragma unroll
  for (int j = 0; j < 8; ++j) { sel[j] = mp[t * 8 + j] > 0.5f; c += sel[j]; }
  int sc = c;
#pragma unroll
  for (int off = 1; off < 64; off <<= 1) {
    int u = __shfl_up(sc, off);
    if (lane >= off) sc += u;
  }
  if (lane == 63) wsum[wv] = sc;
  __syncthreads();
  int woff = 0;
  for (int i = 0; i < wv; ++i) woff += wsum[i];
  int pos = woff + sc - c;   // exclusive prefix
#pragma unroll
  for (int j = 0; j < 8; ++j)
    if (sel[j]) idx[b * 1024 + pos++] = t * 8 + j;
}

// ---------- V transpose: V[b,s,h*64+d] -> VT[bh][d][s] ----------
__global__ void k_vtrans(const u16* __restrict__ V, u16* __restrict__ VT) {
  int bh = blockIdx.y;
  int b = bh >> 4, h = bh & 15;
  int w = threadIdx.x >> 6, l = threadIdx.x & 63;
  int s0 = (blockIdx.x * 4 + w) * 32;
  const u16* vb = V + ((size_t)b * 2048) * 1024 + h * 64 + l;
  u16 vals[32];
#pragma unroll
  for (int j = 0; j < 32; ++j) vals[j] = vb[(size_t)(s0 + j) * 1024];
  u16* ob = VT + ((size_t)bh * 64 + l) * 2048 + s0;
#pragma unroll
  for (int c = 0; c < 4; ++c) {
    short8 o;
#pragma unroll
    for (int j = 0; j < 8; ++j) o[j] = (short)vals[c * 8 + j];
    *(short8*)&ob[c * 8] = o;
  }
}

// ---------- common 128x128 GEMM core over K-slice (256 threads, 4 waves) ----------
__device__ __forceinline__ void gemm_core64(
    const u16* __restrict__ A, const u16* __restrict__ W,
    u16 (&Al)[2][128][64], u16 (&Bl)[2][128][64],
    int m0, int n0, int K, int k0, int nsteps, f32x4 (&acc)[4][4]) {
  const int tid = threadIdx.x, w = tid >> 6, l = tid & 63;
  const int wr = (w >> 1) * 64, wc = (w & 1) * 64;
#pragma unroll
  for (int mt = 0; mt < 4; ++mt)
#pragma unroll
    for (int nt = 0; nt < 4; ++nt) acc[mt][nt] = (f32x4){0.f, 0.f, 0.f, 0.f};

  auto stage = [&](int bf, int t) {
#pragma unroll
    for (int i = 0; i < 4; ++i) {
      const int bc = (i * 4 + w) * 64;
      const int chunk = bc + l;
      const int row = chunk >> 3, cc = chunk & 7;
      gld16(A + (size_t)(m0 + row) * K + k0 + t * 64 + cc * 8, (char*)(&Al[bf][0][0]) + bc * 16);
      gld16(W + (size_t)(n0 + row) * K + k0 + t * 64 + cc * 8, (char*)(&Bl[bf][0][0]) + bc * 16);
    }
  };

  stage(0, 0);
  for (int t = 0; t < nsteps; ++t) {
    __syncthreads();
    if (t + 1 < nsteps) stage((t + 1) & 1, t + 1);
    const int bf = t & 1;
#pragma unroll
    for (int kk = 0; kk < 2; ++kk) {
      const int ko = kk * 32 + (l >> 4) * 8;
      short8 af[4], bv[4];
#pragma unroll
      for (int mt = 0; mt < 4; ++mt) af[mt] = *(const short8*)&Al[bf][wr + mt * 16 + (l & 15)][ko];
#pragma unroll
      for (int nt = 0; nt < 4; ++nt) bv[nt] = *(const short8*)&Bl[bf][wc + nt * 16 + (l & 15)][ko];
#pragma unroll
      for (int mt = 0; mt < 4; ++mt)
#pragma unroll
        for (int nt = 0; nt < 4; ++nt)
          acc[mt][nt] = mfma16(af[mt], bv[nt], acc[mt][nt]);
    }
  }
}

// ---------- QKV v3: BK=32, 32KB LDS, 3 blocks/CU -> all 640 blocks resident ----------
__global__ __launch_bounds__(256, 3)
void k_qkv2(const u16* __restrict__ A, const int* __restrict__ idx,
            const u16* __restrict__ Wq, const u16* __restrict__ Wk, const u16* __restrict__ Wv,
            u16* __restrict__ Qc, u16* __restrict__ Ko, u16* __restrict__ Vo) {
  __shared__ alignas(16) u16 Al[2][128][32];
  __shared__ alignas(16) u16 Bl[2][128][32];
  const int tid = threadIdx.x, w = tid >> 6, l = tid & 63;
  const int b = blockIdx.x, xcd = b & 7, j = b >> 3;
  const u16* W; u16* Ot; int m0, n0; bool isQ;
  if (j < 16) {
    isQ = true;
    int rowg = (xcd >> 1) * 4 + (j >> 2);
    int col  = (xcd & 1) * 4 + (j & 3);
    m0 = rowg * 128; n0 = col * 128; W = Wq; Ot = Qc;
  } else {
    isQ = false;
    int jj = j - 16;
    int rowg = (xcd >> 1) * 8 + (jj >> 3);
    int colg = (xcd & 1) * 8 + (jj & 7);
    m0 = rowg * 128; n0 = (colg & 7) * 128;
    W = (colg >> 3) ? Wv : Wk; Ot = (colg >> 3) ? Vo : Ko;
  }
  int srow[2];
#pragma unroll
  for (int i = 0; i < 2; ++i) {
    int r = (i * 256 + tid) >> 2;
    int row = m0 + r;
    if (isQ) {
      int b2 = row >> 10;
      srow[i] = b2 * 2048 + idx[b2 * 1024 + (row & 1023)];
    } else srow[i] = row;
  }
  const int wr = (w >> 1) * 64, wc = (w & 1) * 64;
  f32x4 acc[4][4];
#pragma unroll
  for (int mt = 0; mt < 4; ++mt)
#pragma unroll
    for (int nt = 0; nt < 4; ++nt) acc[mt][nt] = (f32x4){0.f, 0.f, 0.f, 0.f};

  auto stage = [&](int bf, int t) {
#pragma unroll
    for (int i = 0; i < 2; ++i) {
      const int c = i * 256 + tid;
      const int r = c >> 2, cc = c & 3;
      gld16(A + (size_t)srow[i] * 1024 + t * 32 + cc * 8, (char*)(&Al[bf][0][0]) + c * 16);
      gld16(W + (size_t)(n0 + r) * 1024 + t * 32 + cc * 8, (char*)(&Bl[bf][0][0]) + c * 16);
    }
  };

  stage(0, 0);
  for (int t = 0; t < 32; ++t) {
    __syncthreads();
    if (t + 1 < 32) stage((t + 1) & 1, t + 1);
    const int bf = t & 1;
    const int ko = (l >> 4) * 8;
    short8 af[4], bv[4];
#pragma unroll
    for (int mt = 0; mt < 4; ++mt) af[mt] = *(const short8*)&Al[bf][wr + mt * 16 + (l & 15)][ko];
#pragma unroll
    for (int nt = 0; nt < 4; ++nt) bv[nt] = *(const short8*)&Bl[bf][wc + nt * 16 + (l & 15)][ko];
#pragma unroll
    for (int mt = 0; mt < 4; ++mt)
#pragma unroll
      for (int nt = 0; nt < 4; ++nt)
        acc[mt][nt] = mfma16(af[mt], bv[nt], acc[mt][nt]);
  }
#pragma unroll
  for (int mt = 0; mt < 4; ++mt)
#pragma unroll
    for (int nt = 0; nt < 4; ++nt) {
      int row = m0 + wr + mt * 16 + ((l >> 4) << 2);
      int colo = n0 + wc + nt * 16 + (l & 15);
#pragma unroll
      for (int r = 0; r < 4; ++r)
        Ot[(size_t)(row + r) * 1024 + colo] = f2bfu(acc[mt][nt][r]);
    }
}

// ---------- split-K projection (REVERTED to 256-thread 4-wave quadrants; R19's
// 512-thread 64x32 split raised per-MFMA LDS traffic 1.5x and regressed) ----------
__global__ __launch_bounds__(256, 2)
void k_projsk(const u16* __restrict__ A, const u16* __restrict__ W,
              float* __restrict__ P0, float* __restrict__ P1,
              float* __restrict__ P2, float* __restrict__ P3,
              int K, int slice) {
  __shared__ alignas(16) u16 Al[2][128][64];
  __shared__ alignas(16) u16 Bl[2][128][64];
  const int b = blockIdx.x, xcd = b & 7, k = b >> 3;
  const int pair = xcd * 8 + (k >> 3);
  const int rowg = pair >> 2, z = pair & 3, col = k & 7;
  const int n0 = col * 128, m0 = rowg * 128, k0 = z * slice;
  float* P = z == 0 ? P0 : (z == 1 ? P1 : (z == 2 ? P2 : P3));
  f32x4 acc[4][4];
  gemm_core64(A, W, Al, Bl, m0, n0, K, k0, slice >> 6, acc);
  const int tid = threadIdx.x, w = tid >> 6, l = tid & 63;
  const int wr = (w >> 1) * 64, wc = (w & 1) * 64;
#pragma unroll
  for (int mt = 0; mt < 4; ++mt)
#pragma unroll
    for (int nt = 0; nt < 4; ++nt) {
      int row = m0 + wr + mt * 16 + ((l >> 4) << 2);
      int colo = n0 + wc + nt * 16 + (l & 15);
#pragma unroll
      for (int r = 0; r < 4; ++r)
        P[(size_t)(row + r) * 1024 + colo] = acc[mt][nt][r];
    }
}

// ---------- combine Z=4 partials + residual, scatter (down-proj final) ----------
__global__ void k_combine(const float* __restrict__ P0, const float* __restrict__ P1,
                          const float* __restrict__ P2, const float* __restrict__ P3,
                          const int* __restrict__ idx, const float* __restrict__ resid,
                          float* __restrict__ out) {
  int slot = blockIdx.x * 2 + (threadIdx.x >> 7);
  int c0 = (threadIdx.x & 127) * 8;
  int b = slot >> 10;
  int orig = idx[b * 1024 + (slot & 1023)];
  size_t po = (size_t)slot * 1024 + c0;
  size_t go = ((size_t)(b * 2048 + orig)) * 1024 + c0;
#pragma unroll
  for (int h = 0; h < 2; ++h) {
    float4 a = *(const float4*)(P0 + po + h * 4);
    float4 bb = *(const float4*)(P1 + po + h * 4);
    float4 c = *(const float4*)(P2 + po + h * 4);
    float4 d = *(const float4*)(P3 + po + h * 4);
    float4 rr = *(const float4*)(resid + go + h * 4);
    float4 o;
    o.x = rr.x + a.x + bb.x + c.x + d.x;
    o.y = rr.y + a.y + bb.y + c.y + d.y;
    o.z = rr.z + a.z + bb.z + c.z + d.z;
    o.w = rr.w + a.w + bb.w + c.w + d.w;
    *(float4*)(out + go + h * 4) = o;
  }
}

// ---------- fused combine(o-proj) + LN2: out_x = x + sum(P); xn2 = LN(out_x) compact ----------
__global__ void k_combine_ln(const float* __restrict__ P0, const float* __restrict__ P1,
                             const float* __restrict__ P2, const float* __restrict__ P3,
                             const int* __restrict__ idx, const float* __restrict__ resid,
                             const float* __restrict__ g, const float* __restrict__ bb,
                             float* __restrict__ out, u16* __restrict__ xn2) {
  __shared__ float red[2][2][2];
  int sh = threadIdx.x >> 7;
  int slot = blockIdx.x * 2 + sh;
  int tl = threadIdx.x & 127;
  int c0 = tl * 8;
  int b = slot >> 10;
  int orig = idx[b * 1024 + (slot & 1023)];
  size_t po = (size_t)slot * 1024 + c0;
  size_t go = ((size_t)(b * 2048 + orig)) * 1024 + c0;
  float v[8];
  float s = 0.f, sq = 0.f;
#pragma unroll
  for (int h = 0; h < 2; ++h) {
    float4 a = *(const float4*)(P0 + po + h * 4);
    float4 b4 = *(const float4*)(P1 + po + h * 4);
    float4 c = *(const float4*)(P2 + po + h * 4);
    float4 d = *(const float4*)(P3 + po + h * 4);
    float4 rr = *(const float4*)(resid + go + h * 4);
    float4 o;
    o.x = rr.x + a.x + b4.x + c.x + d.x;
    o.y = rr.y + a.y + b4.y + c.y + d.y;
    o.z = rr.z + a.z + b4.z + c.z + d.z;
    o.w = rr.w + a.w + b4.w + c.w + d.w;
    *(float4*)(out + go + h * 4) = o;
    v[h * 4 + 0] = o.x; v[h * 4 + 1] = o.y; v[h * 4 + 2] = o.z; v[h * 4 + 3] = o.w;
    s += o.x + o.y + o.z + o.w;
    sq += o.x * o.x + o.y * o.y + o.z * o.z + o.w * o.w;
  }
#pragma unroll
  for (int off = 32; off; off >>= 1) { s += __shfl_xor(s, off); sq += __shfl_xor(sq, off); }
  if ((tl & 63) == 0) { red[sh][tl >> 6][0] = s; red[sh][tl >> 6][1] = sq; }
  __syncthreads();
  float ts = red[sh][0][0] + red[sh][1][0];
  float tsq = red[sh][0][1] + red[sh][1][1];
  float mu = ts * (1.f / 1024.f);
  float var = tsq * (1.f / 1024.f) - mu * mu;
  float rs = rsqrtf(var + 1e-6f);
#pragma unroll
  for (int h = 0; h < 2; ++h) {
    float4 gv = *(const float4*)(g + c0 + h * 4);
    float4 bv = *(const float4*)(bb + c0 + h * 4);
    ushort4v o;
    o.x = f2bfu((v[h * 4 + 0] - mu) * rs * gv.x + bv.x);
    o.y = f2bfu((v[h * 4 + 1] - mu) * rs * gv.y + bv.y);
    o.z = f2bfu((v[h * 4 + 2] - mu) * rs * gv.z + bv.z);
    o.w = f2bfu((v[h * 4 + 3] - mu) * rs * gv.w + bv.w);
    *(ushort4v*)(xn2 + (size_t)slot * 1024 + c0 + h * 4) = o;
  }
}

// ---------- ffn_dual v2: 512 threads, gate/up wave-split, 16 waves/CU ----------
__global__ __launch_bounds__(512, 2)
void k_ffn_dual(const u16* __restrict__ A, const u16* __restrict__ Wg, const u16* __restrict__ Wu,
                u16* __restrict__ H, int N, int K) {
  __shared__ alignas(16) char lds[65536];
  u16 (*Al)[128][32]  = (u16(*)[128][32])(lds);            // 16 KB
  u16 (*Bgl)[128][32] = (u16(*)[128][32])(lds + 16384);    // 16 KB
  u16 (*Bul)[128][32] = (u16(*)[128][32])(lds + 32768);    // 16 KB
  float (*ex)[64]     = (float(*)[64])(lds);               // [256][64] f32 = 64 KB (post-loop)
  const int tid = threadIdx.x, w = tid >> 6, l = tid & 63;
  const int b = blockIdx.x, xcd = b & 7, k = b >> 3;
  const int rowg = (xcd >> 2) * 8 + (k >> 3);   // 0..15
  const int col  = (xcd & 3) * 8 + (k & 7);     // 0..31
  const int n0 = col * 128, m0 = rowg * 128;
  const int q = w & 3;                          // quadrant within 128x128
  const int wr = (q >> 1) * 64, wc = (q & 1) * 64;
  const bool isGate = w < 4;
  f32x4 acc[4][4];
#pragma unroll
  for (int mt = 0; mt < 4; ++mt)
#pragma unroll
    for (int nt = 0; nt < 4; ++nt) acc[mt][nt] = (f32x4){0.f, 0.f, 0.f, 0.f};
  const int nsteps = K >> 5;

  const int srow = tid >> 2, scc = tid & 3;
  auto stage = [&](int bf, int t) {
    gld16(A  + (size_t)(m0 + srow) * K + t * 32 + scc * 8, (char*)(&Al[bf][0][0])  + tid * 16);
    gld16(Wg + (size_t)(n0 + srow) * K + t * 32 + scc * 8, (char*)(&Bgl[bf][0][0]) + tid * 16);
    gld16(Wu + (size_t)(n0 + srow) * K + t * 32 + scc * 8, (char*)(&Bul[bf][0][0]) + tid * 16);
  };

  stage(0, 0);
  for (int t = 0; t < nsteps; ++t) {
    __syncthreads();
    if (t + 1 < nsteps) stage((t + 1) & 1, t + 1);
    const int bf = t & 1;
    const int ko = (l >> 4) * 8;
    short8 af[4], bv[4];
#pragma unroll
    for (int mt = 0; mt < 4; ++mt) af[mt] = *(const short8*)&Al[bf][wr + mt * 16 + (l & 15)][ko];
    if (isGate) {
#pragma unroll
      for (int nt = 0; nt < 4; ++nt) bv[nt] = *(const short8*)&Bgl[bf][wc + nt * 16 + (l & 15)][ko];
    } else {
#pragma unroll
      for (int nt = 0; nt < 4; ++nt) bv[nt] = *(const short8*)&Bul[bf][wc + nt * 16 + (l & 15)][ko];
    }
#pragma unroll
    for (int mt = 0; mt < 4; ++mt)
#pragma unroll
      for (int nt = 0; nt < 4; ++nt)
        acc[mt][nt] = mfma16(af[mt], bv[nt], acc[mt][nt]);
  }

  __syncthreads();
  if (!isGate) {
#pragma unroll
    for (int mt = 0; mt < 4; ++mt)
#pragma unroll
      for (int nt = 0; nt < 4; ++nt)
#pragma unroll
        for (int r = 0; r < 4; ++r)
          ex[((q * 4 + mt) * 4 + nt) * 4 + r][l] = acc[mt][nt][r];
  }
  __syncthreads();
  if (isGate) {
#pragma unroll
    for (int mt = 0; mt < 4; ++mt)
#pragma unroll
      for (int nt = 0; nt < 4; ++nt) {
        int row = m0 + wr + mt * 16 + ((l >> 4) << 2);
        int col2 = n0 + wc + nt * 16 + (l & 15);
#pragma unroll
        for (int r = 0; r < 4; ++r) {
          float gv = acc[mt][nt][r];
          float uu = ex[((q * 4 + mt) * 4 + nt) * 4 + r][l];
          float sg = gv / (1.f + __expf(-gv));
          H[(size_t)(row + r) * N + col2] = f2bfu(sg * uu);
        }
      }
  }
}

// ---------- flash attention v9: fixed-shift softmax (no online max) ----------
__global__ __launch_bounds__(512, 2)
void k_attn(const u16* __restrict__ Q, const u16* __restrict__ K,
            const u16* __restrict__ VT, const int* __restrict__ idx,
            u16* __restrict__ O) {
  const int S = 2048, HH = 1024;
  const int px = blockIdx.x, bh = blockIdx.y;
  const int qt = (bh < 16) ? (15 - px) : px;   // complementary across grid halves
  const int b = bh >> 4, h = bh & 15;
  const int tid = threadIdx.x;
  const int g = tid >> 8;
  const int tg = tid & 255;
  const int w = tg >> 6;
  const int l = tid & 63;
  __shared__ alignas(16) u16 Kl[2][64][72];
  __shared__ alignas(16) u16 Vtl[2][64][72];
  __shared__ alignas(16) char un[20480];           // union: Pl [8][16][72] u16 | cm [4][64][20] f32
  u16 (*Pl)[16][72] = (u16(*)[16][72])un;
  float (*cm)[64][20] = (float(*)[64][20])un;
  const size_t base = ((size_t)b * S) * HH + h * 64;
  const size_t qbase = ((size_t)b * 1024) * HH + h * 64;
  const u16* vtb = VT + ((size_t)bh * 64) * S;
  const int* ib = idx + b * 1024;

  const int r0 = tg >> 3,          cc0 = (tg & 7) * 8;
  const int r1 = (256 + tg) >> 3,  cc1 = (tg & 7) * 8;

  const int slot0 = qt * 64 + w * 16 + ((l >> 4) << 2);
  const int slotA = qt * 64 + w * 16 + (l & 15);
  int qp[4];
#pragma unroll
  for (int r = 0; r < 4; ++r) qp[r] = ib[slot0 + r];
  const int nkt = (ib[qt * 64 + 63] >> 6) + 1;
  const int hh = (nkt + 1) >> 1;
  const int kt_base = g ? hh : 0;
  const int kt_end  = g ? nkt : hh;

  short8 qf[2];
#pragma unroll
  for (int kk = 0; kk < 2; ++kk)
    qf[kk] = *(const short8*)&Q[qbase + (size_t)slotA * HH + kk * 32 + (l >> 4) * 8];

  f32x4 accO[4];
  float ls[4];
#pragma unroll
  for (int dt = 0; dt < 4; ++dt) accO[dt] = (f32x4){0.f, 0.f, 0.f, 0.f};
#pragma unroll
  for (int r = 0; r < 4; ++r) ls[r] = 0.f;

  short8 kreg0, kreg1, vreg0, vreg1;
  auto loadregs = [&](int kt) {
    kreg0 = *(const short8*)&K[base + (size_t)(kt * 64 + r0) * HH + cc0];
    kreg1 = *(const short8*)&K[base + (size_t)(kt * 64 + r1) * HH + cc1];
    vreg0 = *(const short8*)&vtb[(size_t)r0 * S + kt * 64 + cc0];
    vreg1 = *(const short8*)&vtb[(size_t)r1 * S + kt * 64 + cc1];
  };
  if (kt_base < kt_end) loadregs(kt_base);

  for (int i = 0; i < hh; ++i) {
    const int kt = kt_base + i;
    const bool valid = kt < kt_end;
    __syncthreads();
    if (valid) {
      *(short8*)&Kl[g][r0][cc0]  = kreg0;
      *(short8*)&Kl[g][r1][cc1]  = kreg1;
      *(short8*)&Vtl[g][r0][cc0] = vreg0;
      *(short8*)&Vtl[g][r1][cc1] = vreg1;
      if (kt + 1 < kt_end) loadregs(kt + 1);
    }
    __syncthreads();
    if (!valid) continue;

    float p[4][4];
    const int kcb = kt * 64 + (l & 15);
#pragma unroll
    for (int ct = 0; ct < 4; ++ct) {
      f32x4 a = (f32x4){0.f, 0.f, 0.f, 0.f};
#pragma unroll
      for (int kk = 0; kk < 2; ++kk) {
        short8 kf = *(const short8*)&Kl[g][ct * 16 + (l & 15)][kk * 32 + (l >> 4) * 8];
        a = mfma16(qf[kk], kf, a);
      }
#pragma unroll
      for (int r = 0; r < 4; ++r) {
        float v = a[r] * (0.125f * LOG2E) - 16.0f;   // fixed shift C=16
        if ((kcb + ct * 16) > qp[r]) v = -1e30f;      // exp2 -> exactly 0
        p[ct][r] = v;
      }
    }
#pragma unroll
    for (int r = 0; r < 4; ++r) {
      float ps = 0.f;
#pragma unroll
      for (int ct = 0; ct < 4; ++ct) { float e = exp2f(p[ct][r]); p[ct][r] = e; ps += e; }
      ps = rsum16(ps);                        // DPP row-reduce
      ls[r] += ps;
    }
#pragma unroll
    for (int ct = 0; ct < 4; ++ct)
#pragma unroll
      for (int r = 0; r < 4; ++r)
        Pl[g * 4 + w][((l >> 4) << 2) + r][ct * 16 + (l & 15)] = f2bfu(p[ct][r]);
    short8 pa[2];
#pragma unroll
    for (int kk = 0; kk < 2; ++kk)
      pa[kk] = *(const short8*)&Pl[g * 4 + w][l & 15][kk * 32 + (l >> 4) * 8];
#pragma unroll
    for (int dt = 0; dt < 4; ++dt)
#pragma unroll
      for (int kk = 0; kk < 2; ++kk) {
        short8 vf = *(const short8*)&Vtl[g][dt * 16 + (l & 15)][kk * 32 + (l >> 4) * 8];
        accO[dt] = mfma16(pa[kk], vf, accO[dt]);
      }
  }

  // combine group partials: same fixed shift on both sides -> plain sums.
  __syncthreads();
  if (g == 1) {
    float* dst = &cm[w][l][0];
#pragma unroll
    for (int r = 0; r < 4; ++r) dst[r] = ls[r];
#pragma unroll
    for (int dt = 0; dt < 4; ++dt)
#pragma unroll
      for (int r = 0; r < 4; ++r) dst[4 + dt * 4 + r] = accO[dt][r];
  }
  __syncthreads();
  if (g == 0) {
    const float* src = &cm[w][l][0];
#pragma unroll
    for (int r = 0; r < 4; ++r) {
      float lsf = ls[r] + src[r];
      float inv = 1.f / lsf;
#pragma unroll
      for (int dt = 0; dt < 4; ++dt) {
        float v = (accO[dt][r] + src[4 + dt * 4 + r]) * inv;
        O[((size_t)(b * 1024 + slot0 + r)) * HH + h * 64 + dt * 16 + (l & 15)] = f2bfu(v);
      }
    }
  }
}

extern "C" void kernel_launch(void* const* d_in, const int* in_sizes, int n_in,
                              void* d_out, int out_size, void* d_ws, size_t ws_size,
                              hipStream_t stream) {
  const float* x  = (const float*)d_in[0];
  const float* wr = (const float*)d_in[1];
  const float* g1 = (const float*)d_in[2];
  const float* b1 = (const float*)d_in[3];
  const float* wq = (const float*)d_in[4];
  const float* wk = (const float*)d_in[5];
  const float* wv = (const float*)d_in[6];
  const float* wo = (const float*)d_in[7];
  const float* g2 = (const float*)d_in[8];
  const float* b2 = (const float*)d_in[9];
  const float* wg = (const float*)d_in[10];
  const float* wu = (const float*)d_in[11];
  const float* wd = (const float*)d_in[12];

  float* out_x  = (float*)d_out;
  float* out_lg = out_x + (size_t)4096 * 1024;

  char* p = (char*)d_ws;
  float* mask   = (float*)p;             p += 16384;
  float* logits = (float*)p;             p += 16384;
  int*   idx    = (int*)p;               p += 16384;   // [2][1024]
  u16* wq_b = (u16*)p;                   p += (size_t)1048576 * 2;
  u16* wk_b = (u16*)p;                   p += (size_t)1048576 * 2;
  u16* wv_b = (u16*)p;                   p += (size_t)1048576 * 2;
  u16* wo_b = (u16*)p;                   p += (size_t)1048576 * 2;
  u16* wg_b = (u16*)p;                   p += (size_t)4194304 * 2;
  u16* wu_b = (u16*)p;                   p += (size_t)4194304 * 2;
  u16* wd_b = (u16*)p;                   p += (size_t)4194304 * 2;
  u16* xn   = (u16*)p;                   p += (size_t)4194304 * 2;  // 8 MB
  u16* q_b  = (u16*)p;                   p += (size_t)4194304 * 2;  // 8 MB
  u16* k_b  = (u16*)p;                   p += (size_t)4194304 * 2;  // 8 MB
  u16* v_b  = (u16*)p;                   p += (size_t)4194304 * 2;  // 8 MB
  u16* ao_b = (u16*)p;                   p += (size_t)2097152 * 2;  // compact [2048][1024]
  u16* vt_b = (u16*)p;                   p += (size_t)4194304 * 2;  // VT, 8 MB
  float* pextra = (float*)p;             p += (size_t)2097152 * 4;  // 8 MB partial
  u16* h_b  = q_b;  // compact h [2048][4096] bf16 spans q_b+k_b (16 MB)

  // o-proj partials (dead after attn): v_b, k_b, vt_b, pextra
  float* oP0 = (float*)v_b;  float* oP1 = (float*)k_b;
  float* oP2 = (float*)vt_b; float* oP3 = pextra;
  u16* xn2 = xn;             // compact [2048][1024] bf16 in xn region front 4 MB
  // down-proj partials (dead after ffn_dual): v_b, vt_b, pextra, xn
  float* dP0 = (float*)v_b;  float* dP1 = (float*)vt_b;
  float* dP2 = pextra;       float* dP3 = (float*)xn;

  // weight conversions (single launch)
  k_cvt7<<<dim3(4096, 7), 256, 0, stream>>>(wq, wk, wv, wo, wg, wu, wd,
                                            wq_b, wk_b, wv_b, wo_b, wg_b, wu_b, wd_b);

  // fused router + LN1 (+ out_x = x pre-fill), then mask + compact index
  k_router_ln<<<1024, 256, 0, stream>>>(x, wr, g1, b1, logits, out_lg, out_x, xn);
  k_mask<<<dim3(32, 2), 256, 0, stream>>>(logits, mask);
  k_scan<<<2, 256, 0, stream>>>(mask, idx);

  // attention sub-block (Q compact, K/V full)
  k_qkv2<<<640, 256, 0, stream>>>(xn, idx, wq_b, wk_b, wv_b, q_b, k_b, v_b);
  k_vtrans<<<dim3(16, 32), 256, 0, stream>>>(v_b, vt_b);
  k_attn<<<dim3(16, 32), 512, 0, stream>>>(q_b, k_b, vt_b, idx, ao_b);
  // o-proj: split-K=4 partials (slice 256), then fused combine + LN2 -> out_x, xn2
  k_projsk<<<512, 256, 0, stream>>>(ao_b, wo_b, oP0, oP1, oP2, oP3, 1024, 256);
  k_combine_ln<<<1024, 256, 0, stream>>>(oP0, oP1, oP2, oP3, idx, x, g2, b2, out_x, xn2);

  // FFN sub-block (compact M=2048, gate/up wave-split)
  k_ffn_dual<<<512, 512, 0, stream>>>(xn2, wg_b, wu_b, h_b, 4096, 1024);
  // down-proj: split-K=4 partials (slice 1024) + combine with resid = out_x (in place)
  k_projsk<<<512, 256, 0, stream>>>(h_b, wd_b, dP0, dP1, dP2, dP3, 4096, 1024);
  k_combine<<<1024, 256, 0, stream>>>(dP0, dP1, dP2, dP3, idx, out_x, out_x);
}

// Round 21
// 212.704 us; speedup vs baseline: 1.0296x; 1.0180x over previous
//
#include <hip/hip_runtime.h>
#include <hip/hip_bf16.h>

typedef unsigned short u16;
typedef __attribute__((ext_vector_type(4))) float f32x4;
typedef __attribute__((ext_vector_type(8))) short short8;
typedef __attribute__((ext_vector_type(4))) unsigned short ushort4v;

#define LOG2E 1.4426950408889634f

// ---------- helpers ----------
__device__ __forceinline__ u16 f2bfu(float f) {
  unsigned int u = __float_as_uint(f);
  u += 0x7FFFu + ((u >> 16) & 1u);   // RNE
  return (u16)(u >> 16);
}
__device__ __forceinline__ f32x4 mfma16(short8 a, short8 b, f32x4 c) {
  return __builtin_amdgcn_mfma_f32_16x16x32_bf16(a, b, c, 0, 0, 0);
}
__device__ __forceinline__ void gld16(const void* g, void* l) {
  __builtin_amdgcn_global_load_lds(
      (const __attribute__((address_space(1))) void*)g,
      (__attribute__((address_space(3))) void*)l, 16, 0, 0);
}
// DPP row_ror:N within 16-lane rows (VALU-pipe cross-lane; no LDS)
template <int CTRL>
__device__ __forceinline__ float dppf(float x) {
  int xi = __float_as_int(x);
  return __int_as_float(__builtin_amdgcn_update_dpp(xi, xi, CTRL, 0xf, 0xf, false));
}
__device__ __forceinline__ float rsum16(float v) {
  v += dppf<0x121>(v);
  v += dppf<0x122>(v);
  v += dppf<0x124>(v);
  v += dppf<0x128>(v);
  return v;
}

// ---------- fp32 -> bf16 convert, all 7 weights in one launch ----------
__global__ void k_cvt7(const float* __restrict__ s0, const float* __restrict__ s1,
                       const float* __restrict__ s2, const float* __restrict__ s3,
                       const float* __restrict__ s4, const float* __restrict__ s5,
                       const float* __restrict__ s6,
                       u16* __restrict__ d0, u16* __restrict__ d1, u16* __restrict__ d2,
                       u16* __restrict__ d3, u16* __restrict__ d4, u16* __restrict__ d5,
                       u16* __restrict__ d6) {
  const int y = blockIdx.y;
  const float* src; u16* dst; int n4;
  switch (y) {
    case 0: src = s0; dst = d0; n4 = 262144; break;
    case 1: src = s1; dst = d1; n4 = 262144; break;
    case 2: src = s2; dst = d2; n4 = 262144; break;
    case 3: src = s3; dst = d3; n4 = 262144; break;
    case 4: src = s4; dst = d4; n4 = 1048576; break;
    case 5: src = s5; dst = d5; n4 = 1048576; break;
    default: src = s6; dst = d6; n4 = 1048576; break;
  }
  int i = blockIdx.x * blockDim.x + threadIdx.x;
  if (i < n4) {
    float4 v = ((const float4*)src)[i];
    ushort4v o;
    o.x = f2bfu(v.x); o.y = f2bfu(v.y); o.z = f2bfu(v.z); o.w = f2bfu(v.w);
    *(ushort4v*)(dst + (size_t)i * 4) = o;
  }
}

// ---------- fused router + LN1 + residual pre-fill ----------
__global__ void k_router_ln(const float* __restrict__ x, const float* __restrict__ wr,
                            const float* __restrict__ g, const float* __restrict__ bb,
                            float* __restrict__ logits, float* __restrict__ out_lg,
                            float* __restrict__ out_x, u16* __restrict__ xn) {
  int t = blockIdx.x * 4 + (threadIdx.x >> 6);
  int l = threadIdx.x & 63;
  const float* xp = x + (size_t)t * 1024;
  float* op = out_x + (size_t)t * 1024;
  float4 xv[4];
  float s = 0.f, sq = 0.f, lg = 0.f;
#pragma unroll
  for (int p = 0; p < 4; ++p) {
    xv[p] = *(const float4*)(xp + (p * 64 + l) * 4);
    float4 wv = *(const float4*)(wr + (p * 64 + l) * 4);
    lg += xv[p].x * wv.x + xv[p].y * wv.y + xv[p].z * wv.z + xv[p].w * wv.w;
    s += xv[p].x + xv[p].y + xv[p].z + xv[p].w;
    sq += xv[p].x * xv[p].x + xv[p].y * xv[p].y + xv[p].z * xv[p].z + xv[p].w * xv[p].w;
    *(float4*)(op + (p * 64 + l) * 4) = xv[p];
  }
#pragma unroll
  for (int off = 32; off; off >>= 1) {
    lg += __shfl_xor(lg, off);
    s += __shfl_xor(s, off);
    sq += __shfl_xor(sq, off);
  }
  float mu = s * (1.f / 1024.f);
  float var = sq * (1.f / 1024.f) - mu * mu;
  float rs = rsqrtf(var + 1e-6f);
#pragma unroll
  for (int p = 0; p < 4; ++p) {
    float4 gv = *(const float4*)(g + (p * 64 + l) * 4);
    float4 bv = *(const float4*)(bb + (p * 64 + l) * 4);
    ushort4v o;
    o.x = f2bfu((xv[p].x - mu) * rs * gv.x + bv.x);
    o.y = f2bfu((xv[p].y - mu) * rs * gv.y + bv.y);
    o.z = f2bfu((xv[p].z - mu) * rs * gv.z + bv.z);
    o.w = f2bfu((xv[p].w - mu) * rs * gv.w + bv.w);
    *(ushort4v*)(xn + (size_t)t * 1024 + (p * 64 + l) * 4) = o;
  }
  if (l == 0) { logits[t] = lg; out_lg[t] = lg; }
}

// ---------- top-k mask by rank counting (ties: lower index wins) ----------
__global__ void k_mask(const float* __restrict__ logits, float* __restrict__ mask) {
  __shared__ float lg[2048];
  int b = blockIdx.y;
  const float* lp = logits + b * 2048;
  for (int j = threadIdx.x; j < 2048; j += 256) lg[j] = lp[j];
  __syncthreads();
  int t = threadIdx.x >> 2, qtr = threadIdx.x & 3;
  int i = blockIdx.x * 64 + t;
  float my = lg[i];
  int cnt = 0;
  for (int j = qtr * 512; j < qtr * 512 + 512; j += 4) {
    float4 v = *(const float4*)&lg[j];
    cnt += (v.x > my) || (v.x == my && (j + 0) < i);
    cnt += (v.y > my) || (v.y == my && (j + 1) < i);
    cnt += (v.z > my) || (v.z == my && (j + 2) < i);
    cnt += (v.w > my) || (v.w == my && (j + 3) < i);
  }
  cnt += __shfl_xor(cnt, 1);
  cnt += __shfl_xor(cnt, 2);
  if (qtr == 0) mask[b * 2048 + i] = (cnt < 1024) ? 1.0f : 0.0f;
}

// ---------- compact selected-token index (ascending) via prefix scan ----------
__global__ void k_scan(const float* __restrict__ mask, int* __restrict__ idx) {
  __shared__ int wsum[4];
  int b = blockIdx.x;
  const float* mp = mask + b * 2048;
  int t = threadIdx.x, lane = t & 63, wv = t >> 6;
  int sel[8]; int c = 0;
#pragma unroll
  for (int j = 0; j < 8; ++j) { sel[j] = mp[t * 8 + j] > 0.5f; c += sel[j]; }
  int sc = c;
#pragma unroll
  for (int off = 1; off < 64; off <<= 1) {
    int u = __shfl_up(sc, off);
    if (lane >= off) sc += u;
  }
  if (lane == 63) wsum[wv] = sc;
  __syncthreads();
  int woff = 0;
  for (int i = 0; i < wv; ++i) woff += wsum[i];
  int pos = woff + sc - c;   // exclusive prefix
#pragma unroll
  for (int j = 0; j < 8; ++j)
    if (sel[j]) idx[b * 1024 + pos++] = t * 8 + j;
}

// ---------- common 128x128 GEMM core over K-slice (256 threads, 4 waves) ----------
__device__ __forceinline__ void gemm_core64(
    const u16* __restrict__ A, const u16* __restrict__ W,
    u16 (&Al)[2][128][64], u16 (&Bl)[2][128][64],
    int m0, int n0, int K, int k0, int nsteps, f32x4 (&acc)[4][4]) {
  const int tid = threadIdx.x, w = tid >> 6, l = tid & 63;
  const int wr = (w >> 1) * 64, wc = (w & 1) * 64;
#pragma unroll
  for (int mt = 0; mt < 4; ++mt)
#pragma unroll
    for (int nt = 0; nt < 4; ++nt) acc[mt][nt] = (f32x4){0.f, 0.f, 0.f, 0.f};

  auto stage = [&](int bf, int t) {
#pragma unroll
    for (int i = 0; i < 4; ++i) {
      const int bc = (i * 4 + w) * 64;
      const int chunk = bc + l;
      const int row = chunk >> 3, cc = chunk & 7;
      gld16(A + (size_t)(m0 + row) * K + k0 + t * 64 + cc * 8, (char*)(&Al[bf][0][0]) + bc * 16);
      gld16(W + (size_t)(n0 + row) * K + k0 + t * 64 + cc * 8, (char*)(&Bl[bf][0][0]) + bc * 16);
    }
  };

  stage(0, 0);
  for (int t = 0; t < nsteps; ++t) {
    __syncthreads();
    if (t + 1 < nsteps) stage((t + 1) & 1, t + 1);
    const int bf = t & 1;
#pragma unroll
    for (int kk = 0; kk < 2; ++kk) {
      const int ko = kk * 32 + (l >> 4) * 8;
      short8 af[4], bv[4];
#pragma unroll
      for (int mt = 0; mt < 4; ++mt) af[mt] = *(const short8*)&Al[bf][wr + mt * 16 + (l & 15)][ko];
#pragma unroll
      for (int nt = 0; nt < 4; ++nt) bv[nt] = *(const short8*)&Bl[bf][wc + nt * 16 + (l & 15)][ko];
#pragma unroll
      for (int mt = 0; mt < 4; ++mt)
#pragma unroll
        for (int nt = 0; nt < 4; ++nt)
          acc[mt][nt] = mfma16(af[mt], bv[nt], acc[mt][nt]);
    }
  }
}

// ---------- QKV v4: BK=32, 3 blocks/CU; V blocks write VT[bh][d][s] DIRECTLY ----------
// (k_vtrans deleted: V's epilogue does the transpose — 4 consecutive acc rows are
//  consecutive s -> one aligned 8B ushort4 store per fragment.)
__global__ __launch_bounds__(256, 3)
void k_qkv2(const u16* __restrict__ A, const int* __restrict__ idx,
            const u16* __restrict__ Wq, const u16* __restrict__ Wk, const u16* __restrict__ Wv,
            u16* __restrict__ Qc, u16* __restrict__ Ko, u16* __restrict__ VTo) {
  __shared__ alignas(16) u16 Al[2][128][32];
  __shared__ alignas(16) u16 Bl[2][128][32];
  const int tid = threadIdx.x, w = tid >> 6, l = tid & 63;
  const int b = blockIdx.x, xcd = b & 7, j = b >> 3;
  const u16* W; u16* Ot = nullptr; int m0, n0; bool isQ, isV = false;
  if (j < 16) {
    isQ = true;
    int rowg = (xcd >> 1) * 4 + (j >> 2);
    int col  = (xcd & 1) * 4 + (j & 3);
    m0 = rowg * 128; n0 = col * 128; W = Wq; Ot = Qc;
  } else {
    isQ = false;
    int jj = j - 16;
    int rowg = (xcd >> 1) * 8 + (jj >> 3);
    int colg = (xcd & 1) * 8 + (jj & 7);
    m0 = rowg * 128; n0 = (colg & 7) * 128;
    isV = (colg >> 3) != 0;
    W = isV ? Wv : Wk; Ot = isV ? nullptr : Ko;
  }
  int srow[2];
#pragma unroll
  for (int i = 0; i < 2; ++i) {
    int r = (i * 256 + tid) >> 2;
    int row = m0 + r;
    if (isQ) {
      int b2 = row >> 10;
      srow[i] = b2 * 2048 + idx[b2 * 1024 + (row & 1023)];
    } else srow[i] = row;
  }
  const int wr = (w >> 1) * 64, wc = (w & 1) * 64;
  f32x4 acc[4][4];
#pragma unroll
  for (int mt = 0; mt < 4; ++mt)
#pragma unroll
    for (int nt = 0; nt < 4; ++nt) acc[mt][nt] = (f32x4){0.f, 0.f, 0.f, 0.f};

  auto stage = [&](int bf, int t) {
#pragma unroll
    for (int i = 0; i < 2; ++i) {
      const int c = i * 256 + tid;
      const int r = c >> 2, cc = c & 3;
      gld16(A + (size_t)srow[i] * 1024 + t * 32 + cc * 8, (char*)(&Al[bf][0][0]) + c * 16);
      gld16(W + (size_t)(n0 + r) * 1024 + t * 32 + cc * 8, (char*)(&Bl[bf][0][0]) + c * 16);
    }
  };

  stage(0, 0);
  for (int t = 0; t < 32; ++t) {
    __syncthreads();
    if (t + 1 < 32) stage((t + 1) & 1, t + 1);
    const int bf = t & 1;
    const int ko = (l >> 4) * 8;
    short8 af[4], bv[4];
#pragma unroll
    for (int mt = 0; mt < 4; ++mt) af[mt] = *(const short8*)&Al[bf][wr + mt * 16 + (l & 15)][ko];
#pragma unroll
    for (int nt = 0; nt < 4; ++nt) bv[nt] = *(const short8*)&Bl[bf][wc + nt * 16 + (l & 15)][ko];
#pragma unroll
    for (int mt = 0; mt < 4; ++mt)
#pragma unroll
      for (int nt = 0; nt < 4; ++nt)
        acc[mt][nt] = mfma16(af[mt], bv[nt], acc[mt][nt]);
  }
  if (isV) {
    // transposed write: VT[(b*16+h)*64+d][s]; 4 consecutive r = consecutive s
#pragma unroll
    for (int mt = 0; mt < 4; ++mt)
#pragma unroll
      for (int nt = 0; nt < 4; ++nt) {
        int row = m0 + wr + mt * 16 + ((l >> 4) << 2);   // global s index (0..4095)
        int col = n0 + wc + nt * 16 + (l & 15);          // h*64 + d
        int b2 = row >> 11, sl = row & 2047;
        int h2 = col >> 6, dd = col & 63;
        ushort4v o;
        o.x = f2bfu(acc[mt][nt][0]);
        o.y = f2bfu(acc[mt][nt][1]);
        o.z = f2bfu(acc[mt][nt][2]);
        o.w = f2bfu(acc[mt][nt][3]);
        *(ushort4v*)&VTo[(((size_t)(b2 * 16 + h2) * 64) + dd) * 2048 + sl] = o;
      }
  } else {
#pragma unroll
    for (int mt = 0; mt < 4; ++mt)
#pragma unroll
      for (int nt = 0; nt < 4; ++nt) {
        int row = m0 + wr + mt * 16 + ((l >> 4) << 2);
        int colo = n0 + wc + nt * 16 + (l & 15);
#pragma unroll
        for (int r = 0; r < 4; ++r)
          Ot[(size_t)(row + r) * 1024 + colo] = f2bfu(acc[mt][nt][r]);
      }
  }
}

// ---------- split-K projection (256-thread 4-wave quadrants) ----------
__global__ __launch_bounds__(256, 2)
void k_projsk(const u16* __restrict__ A, const u16* __restrict__ W,
              float* __restrict__ P0, float* __restrict__ P1,
              float* __restrict__ P2, float* __restrict__ P3,
              int K, int slice) {
  __shared__ alignas(16) u16 Al[2][128][64];
  __shared__ alignas(16) u16 Bl[2][128][64];
  const int b = blockIdx.x, xcd = b & 7, k = b >> 3;
  const int pair = xcd * 8 + (k >> 3);
  const int rowg = pair >> 2, z = pair & 3, col = k & 7;
  const int n0 = col * 128, m0 = rowg * 128, k0 = z * slice;
  float* P = z == 0 ? P0 : (z == 1 ? P1 : (z == 2 ? P2 : P3));
  f32x4 acc[4][4];
  gemm_core64(A, W, Al, Bl, m0, n0, K, k0, slice >> 6, acc);
  const int tid = threadIdx.x, w = tid >> 6, l = tid & 63;
  const int wr = (w >> 1) * 64, wc = (w & 1) * 64;
#pragma unroll
  for (int mt = 0; mt < 4; ++mt)
#pragma unroll
    for (int nt = 0; nt < 4; ++nt) {
      int row = m0 + wr + mt * 16 + ((l >> 4) << 2);
      int colo = n0 + wc + nt * 16 + (l & 15);
#pragma unroll
      for (int r = 0; r < 4; ++r)
        P[(size_t)(row + r) * 1024 + colo] = acc[mt][nt][r];
    }
}

// ---------- combine Z=4 partials + residual, scatter (down-proj final) ----------
__global__ void k_combine(const float* __restrict__ P0, const float* __restrict__ P1,
                          const float* __restrict__ P2, const float* __restrict__ P3,
                          const int* __restrict__ idx, const float* __restrict__ resid,
                          float* __restrict__ out) {
  int slot = blockIdx.x * 2 + (threadIdx.x >> 7);
  int c0 = (threadIdx.x & 127) * 8;
  int b = slot >> 10;
  int orig = idx[b * 1024 + (slot & 1023)];
  size_t po = (size_t)slot * 1024 + c0;
  size_t go = ((size_t)(b * 2048 + orig)) * 1024 + c0;
#pragma unroll
  for (int h = 0; h < 2; ++h) {
    float4 a = *(const float4*)(P0 + po + h * 4);
    float4 bb = *(const float4*)(P1 + po + h * 4);
    float4 c = *(const float4*)(P2 + po + h * 4);
    float4 d = *(const float4*)(P3 + po + h * 4);
    float4 rr = *(const float4*)(resid + go + h * 4);
    float4 o;
    o.x = rr.x + a.x + bb.x + c.x + d.x;
    o.y = rr.y + a.y + bb.y + c.y + d.y;
    o.z = rr.z + a.z + bb.z + c.z + d.z;
    o.w = rr.w + a.w + bb.w + c.w + d.w;
    *(float4*)(out + go + h * 4) = o;
  }
}

// ---------- fused combine(o-proj) + LN2: out_x = x + sum(P); xn2 = LN(out_x) compact ----------
__global__ void k_combine_ln(const float* __restrict__ P0, const float* __restrict__ P1,
                             const float* __restrict__ P2, const float* __restrict__ P3,
                             const int* __restrict__ idx, const float* __restrict__ resid,
                             const float* __restrict__ g, const float* __restrict__ bb,
                             float* __restrict__ out, u16* __restrict__ xn2) {
  __shared__ float red[2][2][2];
  int sh = threadIdx.x >> 7;
  int slot = blockIdx.x * 2 + sh;
  int tl = threadIdx.x & 127;
  int c0 = tl * 8;
  int b = slot >> 10;
  int orig = idx[b * 1024 + (slot & 1023)];
  size_t po = (size_t)slot * 1024 + c0;
  size_t go = ((size_t)(b * 2048 + orig)) * 1024 + c0;
  float v[8];
  float s = 0.f, sq = 0.f;
#pragma unroll
  for (int h = 0; h < 2; ++h) {
    float4 a = *(const float4*)(P0 + po + h * 4);
    float4 b4 = *(const float4*)(P1 + po + h * 4);
    float4 c = *(const float4*)(P2 + po + h * 4);
    float4 d = *(const float4*)(P3 + po + h * 4);
    float4 rr = *(const float4*)(resid + go + h * 4);
    float4 o;
    o.x = rr.x + a.x + b4.x + c.x + d.x;
    o.y = rr.y + a.y + b4.y + c.y + d.y;
    o.z = rr.z + a.z + b4.z + c.z + d.z;
    o.w = rr.w + a.w + b4.w + c.w + d.w;
    *(float4*)(out + go + h * 4) = o;
    v[h * 4 + 0] = o.x; v[h * 4 + 1] = o.y; v[h * 4 + 2] = o.z; v[h * 4 + 3] = o.w;
    s += o.x + o.y + o.z + o.w;
    sq += o.x * o.x + o.y * o.y + o.z * o.z + o.w * o.w;
  }
#pragma unroll
  for (int off = 32; off; off >>= 1) { s += __shfl_xor(s, off); sq += __shfl_xor(sq, off); }
  if ((tl & 63) == 0) { red[sh][tl >> 6][0] = s; red[sh][tl >> 6][1] = sq; }
  __syncthreads();
  float ts = red[sh][0][0] + red[sh][1][0];
  float tsq = red[sh][0][1] + red[sh][1][1];
  float mu = ts * (1.f / 1024.f);
  float var = tsq * (1.f / 1024.f) - mu * mu;
  float rs = rsqrtf(var + 1e-6f);
#pragma unroll
  for (int h = 0; h < 2; ++h) {
    float4 gv = *(const float4*)(g + c0 + h * 4);
    float4 bv = *(const float4*)(bb + c0 + h * 4);
    ushort4v o;
    o.x = f2bfu((v[h * 4 + 0] - mu) * rs * gv.x + bv.x);
    o.y = f2bfu((v[h * 4 + 1] - mu) * rs * gv.y + bv.y);
    o.z = f2bfu((v[h * 4 + 2] - mu) * rs * gv.z + bv.z);
    o.w = f2bfu((v[h * 4 + 3] - mu) * rs * gv.w + bv.w);
    *(ushort4v*)(xn2 + (size_t)slot * 1024 + c0 + h * 4) = o;
  }
}

// ---------- ffn_dual v2: 512 threads, gate/up wave-split, 16 waves/CU ----------
__global__ __launch_bounds__(512, 2)
void k_ffn_dual(const u16* __restrict__ A, const u16* __restrict__ Wg, const u16* __restrict__ Wu,
                u16* __restrict__ H, int N, int K) {
  __shared__ alignas(16) char lds[65536];
  u16 (*Al)[128][32]  = (u16(*)[128][32])(lds);            // 16 KB
  u16 (*Bgl)[128][32] = (u16(*)[128][32])(lds + 16384);    // 16 KB
  u16 (*Bul)[128][32] = (u16(*)[128][32])(lds + 32768);    // 16 KB
  float (*ex)[64]     = (float(*)[64])(lds);               // [256][64] f32 = 64 KB (post-loop)
  const int tid = threadIdx.x, w = tid >> 6, l = tid & 63;
  const int b = blockIdx.x, xcd = b & 7, k = b >> 3;
  const int rowg = (xcd >> 2) * 8 + (k >> 3);   // 0..15
  const int col  = (xcd & 3) * 8 + (k & 7);     // 0..31
  const int n0 = col * 128, m0 = rowg * 128;
  const int q = w & 3;                          // quadrant within 128x128
  const int wr = (q >> 1) * 64, wc = (q & 1) * 64;
  const bool isGate = w < 4;
  f32x4 acc[4][4];
#pragma unroll
  for (int mt = 0; mt < 4; ++mt)
#pragma unroll
    for (int nt = 0; nt < 4; ++nt) acc[mt][nt] = (f32x4){0.f, 0.f, 0.f, 0.f};
  const int nsteps = K >> 5;

  const int srow = tid >> 2, scc = tid & 3;
  auto stage = [&](int bf, int t) {
    gld16(A  + (size_t)(m0 + srow) * K + t * 32 + scc * 8, (char*)(&Al[bf][0][0])  + tid * 16);
    gld16(Wg + (size_t)(n0 + srow) * K + t * 32 + scc * 8, (char*)(&Bgl[bf][0][0]) + tid * 16);
    gld16(Wu + (size_t)(n0 + srow) * K + t * 32 + scc * 8, (char*)(&Bul[bf][0][0]) + tid * 16);
  };

  stage(0, 0);
  for (int t = 0; t < nsteps; ++t) {
    __syncthreads();
    if (t + 1 < nsteps) stage((t + 1) & 1, t + 1);
    const int bf = t & 1;
    const int ko = (l >> 4) * 8;
    short8 af[4], bv[4];
#pragma unroll
    for (int mt = 0; mt < 4; ++mt) af[mt] = *(const short8*)&Al[bf][wr + mt * 16 + (l & 15)][ko];
    if (isGate) {
#pragma unroll
      for (int nt = 0; nt < 4; ++nt) bv[nt] = *(const short8*)&Bgl[bf][wc + nt * 16 + (l & 15)][ko];
    } else {
#pragma unroll
      for (int nt = 0; nt < 4; ++nt) bv[nt] = *(const short8*)&Bul[bf][wc + nt * 16 + (l & 15)][ko];
    }
#pragma unroll
    for (int mt = 0; mt < 4; ++mt)
#pragma unroll
      for (int nt = 0; nt < 4; ++nt)
        acc[mt][nt] = mfma16(af[mt], bv[nt], acc[mt][nt]);
  }

  __syncthreads();
  if (!isGate) {
#pragma unroll
    for (int mt = 0; mt < 4; ++mt)
#pragma unroll
      for (int nt = 0; nt < 4; ++nt)
#pragma unroll
        for (int r = 0; r < 4; ++r)
          ex[((q * 4 + mt) * 4 + nt) * 4 + r][l] = acc[mt][nt][r];
  }
  __syncthreads();
  if (isGate) {
#pragma unroll
    for (int mt = 0; mt < 4; ++mt)
#pragma unroll
      for (int nt = 0; nt < 4; ++nt) {
        int row = m0 + wr + mt * 16 + ((l >> 4) << 2);
        int col2 = n0 + wc + nt * 16 + (l & 15);
#pragma unroll
        for (int r = 0; r < 4; ++r) {
          float gv = acc[mt][nt][r];
          float uu = ex[((q * 4 + mt) * 4 + nt) * 4 + r][l];
          float sg = gv / (1.f + __expf(-gv));
          H[(size_t)(row + r) * N + col2] = f2bfu(sg * uu);
        }
      }
  }
}

// ---------- flash attention v9: fixed-shift softmax (no online max) ----------
__global__ __launch_bounds__(512, 2)
void k_attn(const u16* __restrict__ Q, const u16* __restrict__ K,
            const u16* __restrict__ VT, const int* __restrict__ idx,
            u16* __restrict__ O) {
  const int S = 2048, HH = 1024;
  const int px = blockIdx.x, bh = blockIdx.y;
  const int qt = (bh < 16) ? (15 - px) : px;   // complementary across grid halves
  const int b = bh >> 4, h = bh & 15;
  const int tid = threadIdx.x;
  const int g = tid >> 8;
  const int tg = tid & 255;
  const int w = tg >> 6;
  const int l = tid & 63;
  __shared__ alignas(16) u16 Kl[2][64][72];
  __shared__ alignas(16) u16 Vtl[2][64][72];
  __shared__ alignas(16) char un[20480];           // union: Pl [8][16][72] u16 | cm [4][64][20] f32
  u16 (*Pl)[16][72] = (u16(*)[16][72])un;
  float (*cm)[64][20] = (float(*)[64][20])un;
  const size_t base = ((size_t)b * S) * HH + h * 64;
  const size_t qbase = ((size_t)b * 1024) * HH + h * 64;
  const u16* vtb = VT + ((size_t)bh * 64) * S;
  const int* ib = idx + b * 1024;

  const int r0 = tg >> 3,          cc0 = (tg & 7) * 8;
  const int r1 = (256 + tg) >> 3,  cc1 = (tg & 7) * 8;

  const int slot0 = qt * 64 + w * 16 + ((l >> 4) << 2);
  const int slotA = qt * 64 + w * 16 + (l & 15);
  int qp[4];
#pragma unroll
  for (int r = 0; r < 4; ++r) qp[r] = ib[slot0 + r];
  const int nkt = (ib[qt * 64 + 63] >> 6) + 1;
  const int hh = (nkt + 1) >> 1;
  const int kt_base = g ? hh : 0;
  const int kt_end  = g ? nkt : hh;

  short8 qf[2];
#pragma unroll
  for (int kk = 0; kk < 2; ++kk)
    qf[kk] = *(const short8*)&Q[qbase + (size_t)slotA * HH + kk * 32 + (l >> 4) * 8];

  f32x4 accO[4];
  float ls[4];
#pragma unroll
  for (int dt = 0; dt < 4; ++dt) accO[dt] = (f32x4){0.f, 0.f, 0.f, 0.f};
#pragma unroll
  for (int r = 0; r < 4; ++r) ls[r] = 0.f;

  short8 kreg0, kreg1, vreg0, vreg1;
  auto loadregs = [&](int kt) {
    kreg0 = *(const short8*)&K[base + (size_t)(kt * 64 + r0) * HH + cc0];
    kreg1 = *(const short8*)&K[base + (size_t)(kt * 64 + r1) * HH + cc1];
    vreg0 = *(const short8*)&vtb[(size_t)r0 * S + kt * 64 + cc0];
    vreg1 = *(const short8*)&vtb[(size_t)r1 * S + kt * 64 + cc1];
  };
  if (kt_base < kt_end) loadregs(kt_base);

  for (int i = 0; i < hh; ++i) {
    const int kt = kt_base + i;
    const bool valid = kt < kt_end;
    __syncthreads();
    if (valid) {
      *(short8*)&Kl[g][r0][cc0]  = kreg0;
      *(short8*)&Kl[g][r1][cc1]  = kreg1;
      *(short8*)&Vtl[g][r0][cc0] = vreg0;
      *(short8*)&Vtl[g][r1][cc1] = vreg1;
      if (kt + 1 < kt_end) loadregs(kt + 1);
    }
    __syncthreads();
    if (!valid) continue;

    float p[4][4];
    const int kcb = kt * 64 + (l & 15);
#pragma unroll
    for (int ct = 0; ct < 4; ++ct) {
      f32x4 a = (f32x4){0.f, 0.f, 0.f, 0.f};
#pragma unroll
      for (int kk = 0; kk < 2; ++kk) {
        short8 kf = *(const short8*)&Kl[g][ct * 16 + (l & 15)][kk * 32 + (l >> 4) * 8];
        a = mfma16(qf[kk], kf, a);
      }
#pragma unroll
      for (int r = 0; r < 4; ++r) {
        float v = a[r] * (0.125f * LOG2E) - 16.0f;   // fixed shift C=16
        if ((kcb + ct * 16) > qp[r]) v = -1e30f;      // exp2 -> exactly 0
        p[ct][r] = v;
      }
    }
#pragma unroll
    for (int r = 0; r < 4; ++r) {
      float ps = 0.f;
#pragma unroll
      for (int ct = 0; ct < 4; ++ct) { float e = exp2f(p[ct][r]); p[ct][r] = e; ps += e; }
      ps = rsum16(ps);                        // DPP row-reduce
      ls[r] += ps;
    }
#pragma unroll
    for (int ct = 0; ct < 4; ++ct)
#pragma unroll
      for (int r = 0; r < 4; ++r)
        Pl[g * 4 + w][((l >> 4) << 2) + r][ct * 16 + (l & 15)] = f2bfu(p[ct][r]);
    short8 pa[2];
#pragma unroll
    for (int kk = 0; kk < 2; ++kk)
      pa[kk] = *(const short8*)&Pl[g * 4 + w][l & 15][kk * 32 + (l >> 4) * 8];
#pragma unroll
    for (int dt = 0; dt < 4; ++dt)
#pragma unroll
      for (int kk = 0; kk < 2; ++kk) {
        short8 vf = *(const short8*)&Vtl[g][dt * 16 + (l & 15)][kk * 32 + (l >> 4) * 8];
        accO[dt] = mfma16(pa[kk], vf, accO[dt]);
      }
  }

  // combine group partials: same fixed shift on both sides -> plain sums.
  __syncthreads();
  if (g == 1) {
    float* dst = &cm[w][l][0];
#pragma unroll
    for (int r = 0; r < 4; ++r) dst[r] = ls[r];
#pragma unroll
    for (int dt = 0; dt < 4; ++dt)
#pragma unroll
      for (int r = 0; r < 4; ++r) dst[4 + dt * 4 + r] = accO[dt][r];
  }
  __syncthreads();
  if (g == 0) {
    const float* src = &cm[w][l][0];
#pragma unroll
    for (int r = 0; r < 4; ++r) {
      float lsf = ls[r] + src[r];
      float inv = 1.f / lsf;
#pragma unroll
      for (int dt = 0; dt < 4; ++dt) {
        float v = (accO[dt][r] + src[4 + dt * 4 + r]) * inv;
        O[((size_t)(b * 1024 + slot0 + r)) * HH + h * 64 + dt * 16 + (l & 15)] = f2bfu(v);
      }
    }
  }
}

extern "C" void kernel_launch(void* const* d_in, const int* in_sizes, int n_in,
                              void* d_out, int out_size, void* d_ws, size_t ws_size,
                              hipStream_t stream) {
  const float* x  = (const float*)d_in[0];
  const float* wr = (const float*)d_in[1];
  const float* g1 = (const float*)d_in[2];
  const float* b1 = (const float*)d_in[3];
  const float* wq = (const float*)d_in[4];
  const float* wk = (const float*)d_in[5];
  const float* wv = (const float*)d_in[6];
  const float* wo = (const float*)d_in[7];
  const float* g2 = (const float*)d_in[8];
  const float* b2 = (const float*)d_in[9];
  const float* wg = (const float*)d_in[10];
  const float* wu = (const float*)d_in[11];
  const float* wd = (const float*)d_in[12];

  float* out_x  = (float*)d_out;
  float* out_lg = out_x + (size_t)4096 * 1024;

  char* p = (char*)d_ws;
  float* mask   = (float*)p;             p += 16384;
  float* logits = (float*)p;             p += 16384;
  int*   idx    = (int*)p;               p += 16384;   // [2][1024]
  u16* wq_b = (u16*)p;                   p += (size_t)1048576 * 2;
  u16* wk_b = (u16*)p;                   p += (size_t)1048576 * 2;
  u16* wv_b = (u16*)p;                   p += (size_t)1048576 * 2;
  u16* wo_b = (u16*)p;                   p += (size_t)1048576 * 2;
  u16* wg_b = (u16*)p;                   p += (size_t)4194304 * 2;
  u16* wu_b = (u16*)p;                   p += (size_t)4194304 * 2;
  u16* wd_b = (u16*)p;                   p += (size_t)4194304 * 2;
  u16* xn   = (u16*)p;                   p += (size_t)4194304 * 2;  // 8 MB
  u16* q_b  = (u16*)p;                   p += (size_t)4194304 * 2;  // 8 MB
  u16* k_b  = (u16*)p;                   p += (size_t)4194304 * 2;  // 8 MB
  u16* v_b  = (u16*)p;                   p += (size_t)4194304 * 2;  // 8 MB (partials only now)
  u16* ao_b = (u16*)p;                   p += (size_t)2097152 * 2;  // compact [2048][1024]
  u16* vt_b = (u16*)p;                   p += (size_t)4194304 * 2;  // VT, 8 MB (written by qkv2)
  float* pextra = (float*)p;             p += (size_t)2097152 * 4;  // 8 MB partial
  u16* h_b  = q_b;  // compact h [2048][4096] bf16 spans q_b+k_b (16 MB)

  // o-proj partials (dead after attn): v_b, k_b, vt_b, pextra
  float* oP0 = (float*)v_b;  float* oP1 = (float*)k_b;
  float* oP2 = (float*)vt_b; float* oP3 = pextra;
  u16* xn2 = xn;             // compact [2048][1024] bf16 in xn region front 4 MB
  // down-proj partials (dead after ffn_dual): v_b, vt_b, pextra, xn
  float* dP0 = (float*)v_b;  float* dP1 = (float*)vt_b;
  float* dP2 = pextra;       float* dP3 = (float*)xn;

  // weight conversions (single launch)
  k_cvt7<<<dim3(4096, 7), 256, 0, stream>>>(wq, wk, wv, wo, wg, wu, wd,
                                            wq_b, wk_b, wv_b, wo_b, wg_b, wu_b, wd_b);

  // fused router + LN1 (+ out_x = x pre-fill), then mask + compact index
  k_router_ln<<<1024, 256, 0, stream>>>(x, wr, g1, b1, logits, out_lg, out_x, xn);
  k_mask<<<dim3(32, 2), 256, 0, stream>>>(logits, mask);
  k_scan<<<2, 256, 0, stream>>>(mask, idx);

  // attention sub-block (Q compact; V written directly transposed -> no k_vtrans)
  k_qkv2<<<640, 256, 0, stream>>>(xn, idx, wq_b, wk_b, wv_b, q_b, k_b, vt_b);
  k_attn<<<dim3(16, 32), 512, 0, stream>>>(q_b, k_b, vt_b, idx, ao_b);
  // o-proj: split-K=4 partials (slice 256), then fused combine + LN2 -> out_x, xn2
  k_projsk<<<512, 256, 0, stream>>>(ao_b, wo_b, oP0, oP1, oP2, oP3, 1024, 256);
  k_combine_ln<<<1024, 256, 0, stream>>>(oP0, oP1, oP2, oP3, idx, x, g2, b2, out_x, xn2);

  // FFN sub-block (compact M=2048, gate/up wave-split)
  k_ffn_dual<<<512, 512, 0, stream>>>(xn2, wg_b, wu_b, h_b, 4096, 1024);
  // down-proj: split-K=4 partials (slice 1024) + combine with resid = out_x (in place)
  k_projsk<<<512, 256, 0, stream>>>(h_b, wd_b, dP0, dP1, dP2, dP3, 4096, 1024);
  k_combine<<<1024, 256, 0, stream>>>(dP0, dP1, dP2, dP3, idx, out_x, out_x);
}